// Round 5
// baseline (760.179 us; speedup 1.0000x reference)
//
#include <hip/hip_runtime.h>

typedef __bf16 bf16;
typedef __bf16 bf16x8 __attribute__((ext_vector_type(8)));
typedef __bf16 bf16x4 __attribute__((ext_vector_type(4)));
typedef float  f32x4  __attribute__((ext_vector_type(4)));

__device__ __forceinline__ f32x4 mfma16(bf16x8 a, bf16x8 b, f32x4 c) {
    return __builtin_amdgcn_mfma_f32_16x16x32_bf16(a, b, c, 0, 0, 0);
}

// ---------------- K0: weight repack (BqT scaled+deinterleaved, kvWT, projT) ----------------
__global__ __launch_bounds__(256) void prep_weights(
    const float* __restrict__ qkv_w, const float* __restrict__ qkv_b,
    const float* __restrict__ proj_w,
    bf16* __restrict__ BqT, bf16* __restrict__ kvWT, bf16* __restrict__ projWT,
    float* __restrict__ bkv)
{
    int i = blockIdx.x * 256 + threadIdx.x;
    if (i < 262144) {
        int c_ = i >> 9, k = i & 511;
        int c = (c_ >> 6) * 192 + (c_ & 63) * 3;
        BqT[i] = (bf16)(qkv_w[k * 1536 + c] * 0.125f);
        return;
    }
    i -= 262144;
    if (i < 131072) {
        int c2 = i >> 9, k = i & 511;
        int t = c2 >> 7, kk = (c2 >> 6) & 1, e = c2 & 63;
        int c = t * 192 + e * 3 + 1 + kk;
        kvWT[i] = (bf16)(qkv_w[k * 1536 + c]);
        return;
    }
    i -= 131072;
    if (i < 262144) {
        int c_ = i >> 9, k = i & 511;
        projWT[i] = (bf16)(proj_w[k * 512 + c_]);
        return;
    }
    i -= 262144;
    if (i < 256) {
        int t = i >> 7, kk = (i >> 6) & 1, e = i & 63;
        bkv[i] = qkv_b[t * 192 + e * 3 + 1 + kk];
    }
}

// ---------------- K0b: R = pe_w @ Wq_scaled [3][512], bq2 = s*(qkv_b(q) + pe_b@Wq) ----------------
__global__ __launch_bounds__(256) void prep_r(
    const float* __restrict__ qkv_w, const float* __restrict__ qkv_b,
    const float* __restrict__ pe_w, const float* __restrict__ pe_b,
    float* __restrict__ R, float* __restrict__ bq2)
{
    int idx = blockIdx.x * 256 + threadIdx.x;   // 2048 items
    int c = idx >> 2, j = idx & 3;
    int qc = (c >> 6) * 192 + (c & 63) * 3;
    const float* wcol = qkv_w + qc;
    float s = 0.f;
    if (j < 3) {
        const float* pw = pe_w + j * 512;
        for (int k = 0; k < 512; ++k) s += pw[k] * wcol[(size_t)k * 1536];
        R[j * 512 + c] = 0.125f * s;
    } else {
        for (int k = 0; k < 512; ++k) s += pe_b[k] * wcol[(size_t)k * 1536];
        bq2[c] = 0.125f * (qkv_b[qc] + s);
    }
}

// ---------------- K0c: rel[t][3] = pos - ball mean ----------------
__global__ __launch_bounds__(64) void relprep(const float* __restrict__ pos,
                                              float* __restrict__ rel)
{
    const int t = blockIdx.x * 64 + threadIdx.x;
    float p0 = pos[(size_t)t * 3 + 0];
    float p1 = pos[(size_t)t * 3 + 1];
    float p2 = pos[(size_t)t * 3 + 2];
    float s0 = p0, s1 = p1, s2 = p2;
    #pragma unroll
    for (int m = 1; m < 64; m <<= 1) {
        s0 += __shfl_xor(s0, m);
        s1 += __shfl_xor(s1, m);
        s2 += __shfl_xor(s2, m);
    }
    rel[(size_t)t * 3 + 0] = p0 - s0 * (1.0f / 64.0f);
    rel[(size_t)t * 3 + 1] = p1 - s1 * (1.0f / 64.0f);
    rel[(size_t)t * 3 + 2] = p2 - s2 * (1.0f / 64.0f);
}

// ---------------- K2: k_sel / v_selT (x' recomputed inline for 1024 tokens) ----------------
__global__ __launch_bounds__(256) void kv_proj2(
    const float* __restrict__ x, const float* __restrict__ rel,
    const float* __restrict__ pe_w, const float* __restrict__ pe_b,
    const bf16* __restrict__ kvWT, const float* __restrict__ bkv,
    bf16* __restrict__ ksel, bf16* __restrict__ vselT)
{
    const int bid = blockIdx.x;      // 1024 = 2 b * 8 balls * 64 m2
    const int b = bid >> 9;
    const int ball = (bid >> 6) & 7;
    const int m2 = bid & 63;
    const size_t tok = (size_t)b * 65536 + ball * 64 + m2;
    const int tid = threadIdx.x;

    __shared__ __align__(16) bf16 xrow[512];
    __shared__ float relt[3];
    if (tid < 3) relt[tid] = rel[tok * 3 + tid];
    __syncthreads();
    for (int k = tid; k < 512; k += 256) {
        float v = x[tok * 512 + k] + relt[0] * pe_w[k] + relt[1] * pe_w[512 + k]
                + relt[2] * pe_w[1024 + k] + pe_b[k];
        xrow[k] = (bf16)v;
    }
    __syncthreads();

    float acc = 0.f;
    const bf16* wrp = kvWT + (size_t)tid * 512;
    #pragma unroll 8
    for (int k = 0; k < 512; k += 8) {
        bf16x8 wv = *(const bf16x8*)(wrp + k);
        bf16x8 xv = *(const bf16x8*)(&xrow[k]);
        #pragma unroll
        for (int j = 0; j < 8; ++j) acc += (float)xv[j] * (float)wv[j];
    }
    acc += bkv[tid];
    int t = tid >> 7, kk = (tid >> 6) & 1, e = tid & 63;
    if (kk == 0)
        ksel[((size_t)(b * 8 + ball) * 128 + t * 64 + m2) * 64 + e] = (bf16)acc;
    else
        vselT[((size_t)(b * 8 + ball) * 64 + e) * 128 + t * 64 + m2] = (bf16)acc;
}

// ---------------- K3: fully fused q-GEMM + attention + proj ----------------
// Block = 64 tokens, 4 waves, exactly 2 barriers. All weights/K/V fragments
// read straight from L2 into VGPRs (no staging). One 64 KB LDS buffer holds
// q^T then is overwritten head-by-head with O^T (q_h dead when O_h ready).
// All LDS traffic XOR-swizzled on 16B slots: slot ^= (row & 7).
__global__ __launch_bounds__(256, 2) void fused(
    const float* __restrict__ X, const bf16* __restrict__ BqT,
    const float* __restrict__ rel, const float* __restrict__ R,
    const float* __restrict__ bq2,
    const bf16* __restrict__ ksel, const bf16* __restrict__ vselT,
    const bf16* __restrict__ projT, const float* __restrict__ proj_b,
    float* __restrict__ out)
{
    const int bid = blockIdx.x;                  // 2048
    const int wg = (bid & 7) * 256 + (bid >> 3); // bijective XCD swizzle
    const int b = wg >> 10;
    const size_t tok0 = (size_t)wg * 64;
    const int tid = threadIdx.x;
    const int w = tid >> 6, l = tid & 63;
    const int l15 = l & 15, lg = l >> 4;
    const int r7 = l15 & 7;

    __shared__ __align__(16) char qOb[65536];    // [64 rows][64 16B-slots], swizzled
    __shared__ __align__(16) char Plb[16384];    // [4 waves][16 rows][16 slots], swizzled
    char* myPl = Plb + w * 4096;

    // ================= Phase Q: q^T = BqT @ x^T (+epilogue rel/bias) =================
    {
        f32x4 aq[8][4] = {};   // [mi: qcol 8x16 within wave's 128][nj: token 4x16]
        for (int ks = 0; ks < 16; ++ks) {
            bf16x8 af[8];
            #pragma unroll
            for (int mi = 0; mi < 8; ++mi)
                af[mi] = *(const bf16x8*)(BqT + (size_t)(w * 128 + mi * 16 + l15) * 512 + ks * 32 + lg * 8);
            bf16x8 xb[4];
            #pragma unroll
            for (int nj = 0; nj < 4; ++nj) {
                const float* xp = X + (tok0 + nj * 16 + l15) * 512 + ks * 32 + lg * 8;
                float4 v0 = *(const float4*)xp;
                float4 v1 = *(const float4*)(xp + 4);
                bf16x8 bv = { (bf16)v0.x, (bf16)v0.y, (bf16)v0.z, (bf16)v0.w,
                              (bf16)v1.x, (bf16)v1.y, (bf16)v1.z, (bf16)v1.w };
                xb[nj] = bv;
            }
            #pragma unroll
            for (int mi = 0; mi < 8; ++mi)
                #pragma unroll
                for (int nj = 0; nj < 4; ++nj)
                    aq[mi][nj] = mfma16(af[mi], xb[nj], aq[mi][nj]);
        }
        // epilogue: q[t][c] = aq + bq2[c] + rel[t]·R[:,c]; pack bf16x4 (4 consecutive qcols)
        #pragma unroll
        for (int mi = 0; mi < 8; ++mi) {
            int c0 = w * 128 + mi * 16 + lg * 4;
            float4 R0 = *(const float4*)(R + 0 * 512 + c0);
            float4 R1 = *(const float4*)(R + 1 * 512 + c0);
            float4 R2 = *(const float4*)(R + 2 * 512 + c0);
            float4 BQ = *(const float4*)(bq2 + c0);
            #pragma unroll
            for (int nj = 0; nj < 4; ++nj) {
                int t = nj * 16 + l15;
                const float* rp = rel + (tok0 + t) * 3;
                float rl0 = rp[0], rl1 = rp[1], rl2 = rp[2];
                bf16x4 v;
                v[0] = (bf16)(aq[mi][nj][0] + BQ.x + rl0 * R0.x + rl1 * R1.x + rl2 * R2.x);
                v[1] = (bf16)(aq[mi][nj][1] + BQ.y + rl0 * R0.y + rl1 * R1.y + rl2 * R2.y);
                v[2] = (bf16)(aq[mi][nj][2] + BQ.z + rl0 * R0.z + rl1 * R1.z + rl2 * R2.z);
                v[3] = (bf16)(aq[mi][nj][3] + BQ.w + rl0 * R0.w + rl1 * R1.w + rl2 * R2.w);
                int slot = (w * 16 + mi * 2 + (lg >> 1)) ^ (l15 & 7);
                *(bf16x4*)(qOb + t * 1024 + slot * 16 + (lg & 1) * 8) = v;
            }
        }
    }
    __syncthreads();

    // ================= Phase A: per-head attention, O_h overwrites q_h =================
    // Wave w owns tokens [w*16, w*16+16) — no cross-wave LDS deps, no barriers.
    for (int h = 0; h < 8; ++h) {
        // q A-frags for this head (row = w*16+l15, cols h*64 + lg*8 (+32))
        bf16x8 qa0 = *(const bf16x8*)(qOb + (w * 16 + l15) * 1024 + ((h * 8 + lg) ^ r7) * 16);
        bf16x8 qa1 = *(const bf16x8*)(qOb + (w * 16 + l15) * 1024 + ((h * 8 + 4 + lg) ^ r7) * 16);

        const bf16* kg = ksel + (size_t)(b * 8 + h) * 8192;
        f32x4 s[8];
        #pragma unroll
        for (int kt = 0; kt < 8; ++kt) {
            bf16x8 kf0 = *(const bf16x8*)(kg + (kt * 16 + l15) * 64 + lg * 8);
            bf16x8 kf1 = *(const bf16x8*)(kg + (kt * 16 + l15) * 64 + 32 + lg * 8);
            f32x4 a0 = {0.f, 0.f, 0.f, 0.f};
            a0 = mfma16(qa0, kf0, a0);
            a0 = mfma16(qa1, kf1, a0);
            s[kt] = a0;
        }

        // softmax per token row (reduce over l15-group and kt); P -> myPl[token][kv] swizzled
        #pragma unroll
        for (int r = 0; r < 4; ++r) {
            float mx = s[0][r];
            #pragma unroll
            for (int kt = 1; kt < 8; ++kt) mx = fmaxf(mx, s[kt][r]);
            mx = fmaxf(mx, __shfl_xor(mx, 1));
            mx = fmaxf(mx, __shfl_xor(mx, 2));
            mx = fmaxf(mx, __shfl_xor(mx, 4));
            mx = fmaxf(mx, __shfl_xor(mx, 8));
            float sum = 0.f;
            #pragma unroll
            for (int kt = 0; kt < 8; ++kt) {
                float p = __expf(s[kt][r] - mx);
                s[kt][r] = p;
                sum += p;
            }
            sum += __shfl_xor(sum, 1);
            sum += __shfl_xor(sum, 2);
            sum += __shfl_xor(sum, 4);
            sum += __shfl_xor(sum, 8);
            float inv = 1.0f / sum;
            int prow = lg * 4 + r;
            #pragma unroll
            for (int kt = 0; kt < 8; ++kt) {
                int slot = (kt * 2 + (l15 >> 3)) ^ (prow & 7);
                *(bf16*)(myPl + prow * 256 + slot * 16 + (l15 & 7) * 2) = (bf16)(s[kt][r] * inv);
            }
        }

        // swapped PV: O^T[e][tok]; V-frags straight from L2
        const bf16* vg = vselT + (size_t)(b * 8 + h) * 8192;
        f32x4 o[4] = { {0,0,0,0}, {0,0,0,0}, {0,0,0,0}, {0,0,0,0} };
        #pragma unroll
        for (int kvc = 0; kvc < 4; ++kvc) {
            int slot = (kvc * 4 + lg) ^ r7;
            bf16x8 pb_ = *(const bf16x8*)(myPl + l15 * 256 + slot * 16);
            #pragma unroll
            for (int et = 0; et < 4; ++et) {
                bf16x8 vf = *(const bf16x8*)(vg + (et * 16 + l15) * 128 + kvc * 32 + lg * 8);
                o[et] = mfma16(vf, pb_, o[et]);
            }
        }

        // O-pack: token l15, e = et*16+lg*4+{0..3} contiguous -> 8B swizzled write into q_h slice
        #pragma unroll
        for (int et = 0; et < 4; ++et) {
            bf16x4 ov = { (bf16)o[et][0], (bf16)o[et][1], (bf16)o[et][2], (bf16)o[et][3] };
            int slot = (h * 8 + et * 2 + (lg >> 1)) ^ r7;
            *(bf16x4*)(qOb + (w * 16 + l15) * 1024 + slot * 16 + (lg & 1) * 8) = ov;
        }
    }
    __syncthreads();

    // ================= Phase P: out = O @ projT^T + proj_b =================
    {
        f32x4 ap[4][8] = {};   // [mi: token 4x16][nj: col 8x16 within wave's 128]
        for (int ks = 0; ks < 16; ++ks) {
            bf16x8 af[4];
            #pragma unroll
            for (int mi = 0; mi < 4; ++mi) {
                int slot = (ks * 4 + lg) ^ r7;
                af[mi] = *(const bf16x8*)(qOb + (mi * 16 + l15) * 1024 + slot * 16);
            }
            #pragma unroll
            for (int nj = 0; nj < 8; ++nj) {
                bf16x8 bf_ = *(const bf16x8*)(projT + (size_t)(w * 128 + nj * 16 + l15) * 512 + ks * 32 + lg * 8);
                #pragma unroll
                for (int mi = 0; mi < 4; ++mi)
                    ap[mi][nj] = mfma16(af[mi], bf_, ap[mi][nj]);
            }
        }
        #pragma unroll
        for (int nj = 0; nj < 8; ++nj) {
            int col = w * 128 + nj * 16 + l15;
            float bv = proj_b[col];
            #pragma unroll
            for (int mi = 0; mi < 4; ++mi) {
                size_t rbase = tok0 + mi * 16 + lg * 4;
                #pragma unroll
                for (int r = 0; r < 4; ++r)
                    out[(rbase + r) * 512 + col] = ap[mi][nj][r] + bv;
            }
        }
    }
}

extern "C" void kernel_launch(void* const* d_in, const int* in_sizes, int n_in,
                              void* d_out, int out_size, void* d_ws, size_t ws_size,
                              hipStream_t stream) {
    (void)in_sizes; (void)n_in; (void)out_size; (void)ws_size;
    const float* x      = (const float*)d_in[0];
    const float* pos    = (const float*)d_in[1];
    const float* qkv_w  = (const float*)d_in[2];
    const float* qkv_b  = (const float*)d_in[3];
    const float* proj_w = (const float*)d_in[4];
    const float* proj_b = (const float*)d_in[5];
    const float* pe_w   = (const float*)d_in[6];
    const float* pe_b   = (const float*)d_in[7];

    char* ws = (char*)d_ws;
    bf16*  BqT   = (bf16*)(ws);                 // 524288 B
    bf16*  PjT   = (bf16*)(ws + 524288);        // 524288 B
    bf16*  kvWT  = (bf16*)(ws + 1048576);       // 262144 B
    bf16*  ksel  = (bf16*)(ws + 1310720);       // 262144 B
    bf16*  vselT = (bf16*)(ws + 1572864);       // 262144 B
    float* rel   = (float*)(ws + 1835008);      // 1572864 B
    float* R     = (float*)(ws + 3407872);      // 6144 B
    float* bq2   = (float*)(ws + 3414016);      // 2048 B
    float* bkv   = (float*)(ws + 3416064);      // 1024 B

    prep_weights<<<2561, 256, 0, stream>>>(qkv_w, qkv_b, proj_w, BqT, kvWT, PjT, bkv);
    prep_r<<<8, 256, 0, stream>>>(qkv_w, qkv_b, pe_w, pe_b, R, bq2);
    relprep<<<2048, 64, 0, stream>>>(pos, rel);
    kv_proj2<<<1024, 256, 0, stream>>>(x, rel, pe_w, pe_b, kvWT, bkv, ksel, vselT);
    fused<<<2048, 256, 0, stream>>>(x, BqT, rel, R, bq2, ksel, vselT, PjT, proj_b, (float*)d_out);
}

// Round 6
// 536.352 us; speedup vs baseline: 1.4173x; 1.4173x over previous
//
#include <hip/hip_runtime.h>

typedef __bf16 bf16;
typedef __bf16 bf16x8 __attribute__((ext_vector_type(8)));
typedef __bf16 bf16x4 __attribute__((ext_vector_type(4)));
typedef float  f32x4  __attribute__((ext_vector_type(4)));

__device__ __forceinline__ f32x4 mfma16(bf16x8 a, bf16x8 b, f32x4 c) {
    return __builtin_amdgcn_mfma_f32_16x16x32_bf16(a, b, c, 0, 0, 0);
}

__device__ __forceinline__ void gll16(const bf16* g, bf16* l) {
    __builtin_amdgcn_global_load_lds(
        (const __attribute__((address_space(1))) void*)g,
        (__attribute__((address_space(3))) void*)l, 16, 0, 0);
}

// ---------------- K0: weight repack (BqT scaled+deinterleaved, kvWT, projT) ----------------
__global__ __launch_bounds__(256) void prep_weights(
    const float* __restrict__ qkv_w, const float* __restrict__ qkv_b,
    const float* __restrict__ proj_w,
    bf16* __restrict__ BqT, bf16* __restrict__ kvWT, bf16* __restrict__ projWT,
    float* __restrict__ bkv)
{
    int i = blockIdx.x * 256 + threadIdx.x;
    if (i < 262144) {
        int c_ = i >> 9, k = i & 511;
        int c = (c_ >> 6) * 192 + (c_ & 63) * 3;
        BqT[i] = (bf16)(qkv_w[k * 1536 + c] * 0.125f);
        return;
    }
    i -= 262144;
    if (i < 131072) {
        int c2 = i >> 9, k = i & 511;
        int t = c2 >> 7, kk = (c2 >> 6) & 1, e = c2 & 63;
        int c = t * 192 + e * 3 + 1 + kk;
        kvWT[i] = (bf16)(qkv_w[k * 1536 + c]);
        return;
    }
    i -= 131072;
    if (i < 262144) {
        int c_ = i >> 9, k = i & 511;
        projWT[i] = (bf16)(proj_w[k * 512 + c_]);
        return;
    }
    i -= 262144;
    if (i < 256) {
        int t = i >> 7, kk = (i >> 6) & 1, e = i & 63;
        bkv[i] = qkv_b[t * 192 + e * 3 + 1 + kk];
    }
}

// ---------------- K0b: R = pe_w @ Wq_scaled [3][512], bq2 = s*(qkv_b(q) + pe_b@Wq) ----------------
__global__ __launch_bounds__(256) void prep_r(
    const float* __restrict__ qkv_w, const float* __restrict__ qkv_b,
    const float* __restrict__ pe_w, const float* __restrict__ pe_b,
    float* __restrict__ R, float* __restrict__ bq2)
{
    int idx = blockIdx.x * 256 + threadIdx.x;   // 2048 items
    int c = idx >> 2, j = idx & 3;
    int qc = (c >> 6) * 192 + (c & 63) * 3;
    const float* wcol = qkv_w + qc;
    float s = 0.f;
    if (j < 3) {
        const float* pw = pe_w + j * 512;
        for (int k = 0; k < 512; ++k) s += pw[k] * wcol[(size_t)k * 1536];
        R[j * 512 + c] = 0.125f * s;
    } else {
        for (int k = 0; k < 512; ++k) s += pe_b[k] * wcol[(size_t)k * 1536];
        bq2[c] = 0.125f * (qkv_b[qc] + s);
    }
}

// ---------------- K0c: rel[t][3] = pos - ball mean ----------------
__global__ __launch_bounds__(64) void relprep(const float* __restrict__ pos,
                                              float* __restrict__ rel)
{
    const int t = blockIdx.x * 64 + threadIdx.x;
    float p0 = pos[(size_t)t * 3 + 0];
    float p1 = pos[(size_t)t * 3 + 1];
    float p2 = pos[(size_t)t * 3 + 2];
    float s0 = p0, s1 = p1, s2 = p2;
    #pragma unroll
    for (int m = 1; m < 64; m <<= 1) {
        s0 += __shfl_xor(s0, m);
        s1 += __shfl_xor(s1, m);
        s2 += __shfl_xor(s2, m);
    }
    rel[(size_t)t * 3 + 0] = p0 - s0 * (1.0f / 64.0f);
    rel[(size_t)t * 3 + 1] = p1 - s1 * (1.0f / 64.0f);
    rel[(size_t)t * 3 + 2] = p2 - s2 * (1.0f / 64.0f);
}

// ---------------- K1: Q = bf16(x') @ BqT^T  (pe folded into epilogue) ----------------
// 128x128 tile, 4 waves, BK=64, DOUBLE-BUFFERED (1 barrier / K-step).
// A: f32 reg-staged (issue-early, cvt+ds_write-late). B: global_load_lds.
// Both sides XOR-swizzled (16B slots, slot ^= row&7). XCD-chunked bid swizzle.
__global__ __launch_bounds__(256, 2) void qgemm2(
    const float* __restrict__ X, const bf16* __restrict__ Bt,
    const float* __restrict__ rel, const float* __restrict__ R,
    const float* __restrict__ bq2, bf16* __restrict__ Qout)
{
    const int bid0 = blockIdx.x;
    const int wg = (bid0 & 7) * 512 + (bid0 >> 3);   // bijective
    const int ct = wg & 3;
    const int rt = wg >> 2;
    const int row0 = rt * 128, col0 = ct * 128;
    const int tid = threadIdx.x;
    const int w = tid >> 6, l = tid & 63;
    const int wr = w >> 1, wc = w & 1;
    const int l15 = l & 15, lg = l >> 4;

    __shared__ __align__(16) bf16 Smem[32768];   // 64 KB: [cur][As 8192 | Bs 8192]
    __shared__ float relS[128][3];
    __shared__ float RS[3][128];

    if (tid < 128) {
        relS[tid][0] = rel[(size_t)(row0 + tid) * 3 + 0];
        relS[tid][1] = rel[(size_t)(row0 + tid) * 3 + 1];
        relS[tid][2] = rel[(size_t)(row0 + tid) * 3 + 2];
    } else {
        int c = tid - 128;
        RS[0][c] = R[0 * 512 + col0 + c];
        RS[1][c] = R[1 * 512 + col0 + c];
        RS[2][c] = R[2 * 512 + col0 + c];
    }

    f32x4 acc[4][4] = {};

    // B staging geometry (src pre-swizzled, LDS dest linear)
    int srow[4], scol[4];
    #pragma unroll
    for (int j = 0; j < 4; ++j) {
        int chunk = w * 4 + j;
        int o = chunk * 512 + l * 8;
        int r = o >> 6;
        int slot = (o & 63) >> 3;
        srow[j] = r;
        scol[j] = ((slot ^ (r & 7)) << 3);
    }
    // A reg-staging geometry
    const int ar_sub = l >> 3;
    const int ak = l & 7;
    const int aslot = (ak ^ ar_sub) << 3;

    // prologue: stage tile 0 into buffer 0
    #pragma unroll
    for (int j = 0; j < 4; ++j) {
        int r = (w * 4 + j) * 8 + ar_sub;
        const float* xp = X + (size_t)(row0 + r) * 512 + ak * 8;
        float4 v0 = *(const float4*)xp;
        float4 v1 = *(const float4*)(xp + 4);
        bf16x8 bv = { (bf16)v0.x, (bf16)v0.y, (bf16)v0.z, (bf16)v0.w,
                      (bf16)v1.x, (bf16)v1.y, (bf16)v1.z, (bf16)v1.w };
        *(bf16x8*)&Smem[r * 64 + aslot] = bv;
        gll16(Bt + (size_t)(col0 + srow[j]) * 512 + scol[j], &Smem[8192 + (w * 4 + j) * 512]);
    }
    __syncthreads();

    int cur = 0;
    for (int ki = 0; ki < 8; ++ki) {
        float4 va[4][2];
        if (ki < 7) {
            int ks = (ki + 1) * 64;
            // A: issue next-tile loads (regs)
            #pragma unroll
            for (int j = 0; j < 4; ++j) {
                int r = (w * 4 + j) * 8 + ar_sub;
                const float* xp = X + (size_t)(row0 + r) * 512 + ks + ak * 8;
                va[j][0] = *(const float4*)xp;
                va[j][1] = *(const float4*)(xp + 4);
            }
            // B: async stage next tile into other buffer
            bf16* bdst = &Smem[(cur ^ 1) * 16384 + 8192];
            #pragma unroll
            for (int j = 0; j < 4; ++j)
                gll16(Bt + (size_t)(col0 + srow[j]) * 512 + ks + scol[j], bdst + (w * 4 + j) * 512);
        }
        // compute current buffer
        const bf16* As = &Smem[cur * 16384];
        const bf16* Bs = As + 8192;
        #pragma unroll
        for (int kk = 0; kk < 2; ++kk) {
            bf16x8 a[4], b[4];
            #pragma unroll
            for (int mi = 0; mi < 4; ++mi) {
                int r = wr * 64 + mi * 16 + l15;
                int slot = (kk * 4 + lg) ^ (r & 7);
                a[mi] = *(const bf16x8*)&As[r * 64 + slot * 8];
            }
            #pragma unroll
            for (int ni = 0; ni < 4; ++ni) {
                int r = wc * 64 + ni * 16 + l15;
                int slot = (kk * 4 + lg) ^ (r & 7);
                b[ni] = *(const bf16x8*)&Bs[r * 64 + slot * 8];
            }
            #pragma unroll
            for (int mi = 0; mi < 4; ++mi)
                #pragma unroll
                for (int ni = 0; ni < 4; ++ni)
                    acc[mi][ni] = mfma16(a[mi], b[ni], acc[mi][ni]);
        }
        if (ki < 7) {
            // A: cvt + swizzled write into other buffer (write-late)
            bf16* adst = &Smem[(cur ^ 1) * 16384];
            #pragma unroll
            for (int j = 0; j < 4; ++j) {
                int r = (w * 4 + j) * 8 + ar_sub;
                bf16x8 bv = { (bf16)va[j][0].x, (bf16)va[j][0].y, (bf16)va[j][0].z, (bf16)va[j][0].w,
                              (bf16)va[j][1].x, (bf16)va[j][1].y, (bf16)va[j][1].z, (bf16)va[j][1].w };
                *(bf16x8*)&adst[r * 64 + aslot] = bv;
            }
        }
        __syncthreads();
        cur ^= 1;
    }

    // epilogue: + bias + rel@R, direct bf16 stores
    #pragma unroll
    for (int mi = 0; mi < 4; ++mi) {
        #pragma unroll
        for (int ni = 0; ni < 4; ++ni) {
            int colL = wc * 64 + ni * 16 + l15;
            int col = col0 + colL;
            float bv = bq2[col];
            float r0c = RS[0][colL], r1c = RS[1][colL], r2c = RS[2][colL];
            int rbaseL = wr * 64 + mi * 16 + lg * 4;
            #pragma unroll
            for (int r = 0; r < 4; ++r) {
                int rowL = rbaseL + r;
                float vv = acc[mi][ni][r] + bv
                         + relS[rowL][0] * r0c + relS[rowL][1] * r1c + relS[rowL][2] * r2c;
                Qout[(size_t)(row0 + rowL) * 512 + col] = (bf16)vv;
            }
        }
    }
}

// ---------------- K4: proj GEMM (bf16 A via gll16, f32 out), double-buffered ----------------
__global__ __launch_bounds__(256, 2) void pgemm2(
    const bf16* __restrict__ A, const bf16* __restrict__ Bt,
    const float* __restrict__ bias, float* __restrict__ out)
{
    const int bid0 = blockIdx.x;
    const int wg = (bid0 & 7) * 512 + (bid0 >> 3);
    const int ct = wg & 3;
    const int rt = wg >> 2;
    const int row0 = rt * 128, col0 = ct * 128;
    const int tid = threadIdx.x;
    const int w = tid >> 6, l = tid & 63;
    const int wr = w >> 1, wc = w & 1;
    const int l15 = l & 15, lg = l >> 4;

    __shared__ __align__(16) bf16 Smem[32768];

    f32x4 acc[4][4] = {};

    int srow[4], scol[4];
    #pragma unroll
    for (int j = 0; j < 4; ++j) {
        int chunk = w * 4 + j;
        int o = chunk * 512 + l * 8;
        int r = o >> 6;
        int slot = (o & 63) >> 3;
        srow[j] = r;
        scol[j] = ((slot ^ (r & 7)) << 3);
    }

    // prologue
    #pragma unroll
    for (int j = 0; j < 4; ++j) {
        gll16(A  + (size_t)(row0 + srow[j]) * 512 + scol[j], &Smem[(w * 4 + j) * 512]);
        gll16(Bt + (size_t)(col0 + srow[j]) * 512 + scol[j], &Smem[8192 + (w * 4 + j) * 512]);
    }
    __syncthreads();

    int cur = 0;
    for (int ki = 0; ki < 8; ++ki) {
        if (ki < 7) {
            int ks = (ki + 1) * 64;
            bf16* adst = &Smem[(cur ^ 1) * 16384];
            #pragma unroll
            for (int j = 0; j < 4; ++j) {
                gll16(A  + (size_t)(row0 + srow[j]) * 512 + ks + scol[j], adst + (w * 4 + j) * 512);
                gll16(Bt + (size_t)(col0 + srow[j]) * 512 + ks + scol[j], adst + 8192 + (w * 4 + j) * 512);
            }
        }
        const bf16* As = &Smem[cur * 16384];
        const bf16* Bs = As + 8192;
        #pragma unroll
        for (int kk = 0; kk < 2; ++kk) {
            bf16x8 a[4], b[4];
            #pragma unroll
            for (int mi = 0; mi < 4; ++mi) {
                int r = wr * 64 + mi * 16 + l15;
                int slot = (kk * 4 + lg) ^ (r & 7);
                a[mi] = *(const bf16x8*)&As[r * 64 + slot * 8];
            }
            #pragma unroll
            for (int ni = 0; ni < 4; ++ni) {
                int r = wc * 64 + ni * 16 + l15;
                int slot = (kk * 4 + lg) ^ (r & 7);
                b[ni] = *(const bf16x8*)&Bs[r * 64 + slot * 8];
            }
            #pragma unroll
            for (int mi = 0; mi < 4; ++mi)
                #pragma unroll
                for (int ni = 0; ni < 4; ++ni)
                    acc[mi][ni] = mfma16(a[mi], b[ni], acc[mi][ni]);
        }
        __syncthreads();
        cur ^= 1;
    }

    #pragma unroll
    for (int mi = 0; mi < 4; ++mi) {
        #pragma unroll
        for (int ni = 0; ni < 4; ++ni) {
            int col = col0 + wc * 64 + ni * 16 + l15;
            float bv = bias[col];
            int rbase = row0 + wr * 64 + mi * 16 + lg * 4;
            #pragma unroll
            for (int r = 0; r < 4; ++r)
                out[(size_t)(rbase + r) * 512 + col] = acc[mi][ni][r] + bv;
        }
    }
}

// ---------------- K2: k_sel / v_selT (x' recomputed inline for 1024 tokens) ----------------
__global__ __launch_bounds__(256) void kv_proj2(
    const float* __restrict__ x, const float* __restrict__ rel,
    const float* __restrict__ pe_w, const float* __restrict__ pe_b,
    const bf16* __restrict__ kvWT, const float* __restrict__ bkv,
    bf16* __restrict__ ksel, bf16* __restrict__ vselT)
{
    const int bid = blockIdx.x;
    const int b = bid >> 9;
    const int ball = (bid >> 6) & 7;
    const int m2 = bid & 63;
    const size_t tok = (size_t)b * 65536 + ball * 64 + m2;
    const int tid = threadIdx.x;

    __shared__ __align__(16) bf16 xrow[512];
    __shared__ float relt[3];
    if (tid < 3) relt[tid] = rel[tok * 3 + tid];
    __syncthreads();
    for (int k = tid; k < 512; k += 256) {
        float v = x[tok * 512 + k] + relt[0] * pe_w[k] + relt[1] * pe_w[512 + k]
                + relt[2] * pe_w[1024 + k] + pe_b[k];
        xrow[k] = (bf16)v;
    }
    __syncthreads();

    float acc = 0.f;
    const bf16* wrp = kvWT + (size_t)tid * 512;
    #pragma unroll 8
    for (int k = 0; k < 512; k += 8) {
        bf16x8 wv = *(const bf16x8*)(wrp + k);
        bf16x8 xv = *(const bf16x8*)(&xrow[k]);
        #pragma unroll
        for (int j = 0; j < 8; ++j) acc += (float)xv[j] * (float)wv[j];
    }
    acc += bkv[tid];
    int t = tid >> 7, kk = (tid >> 6) & 1, e = tid & 63;
    if (kk == 0)
        ksel[((size_t)(b * 8 + ball) * 128 + t * 64 + m2) * 64 + e] = (bf16)acc;
    else
        vselT[((size_t)(b * 8 + ball) * 64 + e) * 128 + t * 64 + m2] = (bf16)acc;
}

// ---------------- K3: attention (128 fixed KV per (b,h)), vectorized O-store ----------------
__global__ __launch_bounds__(256) void attn_k(
    const bf16* __restrict__ q, const bf16* __restrict__ ksel,
    const bf16* __restrict__ vselT, bf16* __restrict__ attno)
{
    const int bid = blockIdx.x;      // 16384 = 16 bh * 1024 qtiles
    const int qt = bid & 1023;
    const int bh = bid >> 10;
    const int b = bh >> 3;
    const int h = bh & 7;
    const int tid = threadIdx.x;
    const int w = tid >> 6;
    const int l = tid & 63;
    const int l15 = l & 15, lg = l >> 4;

    __shared__ __align__(16) bf16 Ks[128][72];
    __shared__ __align__(16) bf16 Vt[64][136];
    __shared__ __align__(16) bf16 Pl[4][16][136];

    const bf16* kg = ksel + (size_t)(b * 8 + h) * 128 * 64;
    #pragma unroll
    for (int it = 0; it < 4; ++it) {
        int i = it * 256 + tid;
        int r = i >> 3, c8 = (i & 7) * 8;
        *(bf16x8*)&Ks[r][c8] = *(const bf16x8*)(kg + r * 64 + c8);
    }
    const bf16* vg = vselT + (size_t)(b * 8 + h) * 64 * 128;
    #pragma unroll
    for (int it = 0; it < 4; ++it) {
        int i = it * 256 + tid;
        int r = i >> 4, c8 = (i & 15) * 8;
        *(bf16x8*)&Vt[r][c8] = *(const bf16x8*)(vg + r * 128 + c8);
    }

    const size_t tokq = (size_t)b * 65536 + (size_t)qt * 64 + w * 16 + l15;
    const bf16* qp = q + tokq * 512 + h * 64 + lg * 8;
    bf16x8 qa0 = *(const bf16x8*)qp;
    bf16x8 qa1 = *(const bf16x8*)(qp + 32);

    __syncthreads();

    f32x4 s[8];
    #pragma unroll
    for (int kt = 0; kt < 8; ++kt) {
        f32x4 a0 = {0.f, 0.f, 0.f, 0.f};
        a0 = mfma16(qa0, *(const bf16x8*)&Ks[kt * 16 + l15][lg * 8], a0);
        a0 = mfma16(qa1, *(const bf16x8*)&Ks[kt * 16 + l15][32 + lg * 8], a0);
        s[kt] = a0;
    }

    #pragma unroll
    for (int r = 0; r < 4; ++r) {
        float mx = s[0][r];
        #pragma unroll
        for (int kt = 1; kt < 8; ++kt) mx = fmaxf(mx, s[kt][r]);
        mx = fmaxf(mx, __shfl_xor(mx, 1));
        mx = fmaxf(mx, __shfl_xor(mx, 2));
        mx = fmaxf(mx, __shfl_xor(mx, 4));
        mx = fmaxf(mx, __shfl_xor(mx, 8));
        float sum = 0.f;
        #pragma unroll
        for (int kt = 0; kt < 8; ++kt) {
            float p = __expf(s[kt][r] - mx);
            s[kt][r] = p;
            sum += p;
        }
        sum += __shfl_xor(sum, 1);
        sum += __shfl_xor(sum, 2);
        sum += __shfl_xor(sum, 4);
        sum += __shfl_xor(sum, 8);
        float inv = 1.0f / sum;
        int prow = lg * 4 + r;
        #pragma unroll
        for (int kt = 0; kt < 8; ++kt)
            Pl[w][prow][kt * 16 + l15] = (bf16)(s[kt][r] * inv);
    }

    __syncthreads();

    f32x4 o[4] = { {0,0,0,0}, {0,0,0,0}, {0,0,0,0}, {0,0,0,0} };
    #pragma unroll
    for (int kc = 0; kc < 4; ++kc) {
        bf16x8 pa = *(const bf16x8*)&Pl[w][l15][kc * 32 + lg * 8];
        #pragma unroll
        for (int et = 0; et < 4; ++et)
            o[et] = mfma16(pa, *(const bf16x8*)&Vt[et * 16 + l15][kc * 32 + lg * 8], o[et]);
    }

    // stage O back into this wave's Pl slice (dead after PV), then 16B stores
    #pragma unroll
    for (int et = 0; et < 4; ++et)
        #pragma unroll
        for (int r = 0; r < 4; ++r)
            Pl[w][lg * 4 + r][et * 16 + l15] = (bf16)(o[et][r]);

    __syncthreads();

    {
        int rowg = tid >> 2;
        int w2 = rowg >> 4, lr = rowg & 15;
        int chunk = tid & 3;
        const size_t tok = (size_t)b * 65536 + (size_t)qt * 64 + rowg;
        bf16* gp = attno + tok * 512 + h * 64 + chunk * 16;
        const bf16* lp = &Pl[w2][lr][chunk * 16];
        *(bf16x8*)(gp + 0) = *(const bf16x8*)(lp + 0);
        *(bf16x8*)(gp + 8) = *(const bf16x8*)(lp + 8);
    }
}

extern "C" void kernel_launch(void* const* d_in, const int* in_sizes, int n_in,
                              void* d_out, int out_size, void* d_ws, size_t ws_size,
                              hipStream_t stream) {
    (void)in_sizes; (void)n_in; (void)out_size; (void)ws_size;
    const float* x      = (const float*)d_in[0];
    const float* pos    = (const float*)d_in[1];
    const float* qkv_w  = (const float*)d_in[2];
    const float* qkv_b  = (const float*)d_in[3];
    const float* proj_w = (const float*)d_in[4];
    const float* proj_b = (const float*)d_in[5];
    const float* pe_w   = (const float*)d_in[6];
    const float* pe_b   = (const float*)d_in[7];

    char* ws = (char*)d_ws;
    bf16*  Q     = (bf16*)(ws);                          // 134217728
    bf16*  Z     = (bf16*)(ws + 134217728);              // 134217728 (attn out)
    bf16*  BqT   = (bf16*)(ws + 268435456);              // 524288
    bf16*  PjT   = (bf16*)(ws + 268959744);              // 524288
    bf16*  kvWT  = (bf16*)(ws + 269484032);              // 262144
    bf16*  ksel  = (bf16*)(ws + 269746176);              // 262144
    bf16*  vselT = (bf16*)(ws + 270008320);              // 262144
    float* rel   = (float*)(ws + 270270464);             // 1572864
    float* R     = (float*)(ws + 271843328);             // 6144
    float* bq2   = (float*)(ws + 271849472);             // 2048
    float* bkv   = (float*)(ws + 271851520);             // 1024

    prep_weights<<<2561, 256, 0, stream>>>(qkv_w, qkv_b, proj_w, BqT, kvWT, PjT, bkv);
    prep_r<<<8, 256, 0, stream>>>(qkv_w, qkv_b, pe_w, pe_b, R, bq2);
    relprep<<<2048, 64, 0, stream>>>(pos, rel);
    qgemm2<<<4096, 256, 0, stream>>>(x, BqT, rel, R, bq2, Q);
    kv_proj2<<<1024, 256, 0, stream>>>(x, rel, pe_w, pe_b, kvWT, bkv, ksel, vselT);
    attn_k<<<16384, 256, 0, stream>>>(Q, ksel, vselT, Z);
    pgemm2<<<4096, 256, 0, stream>>>(Z, PjT, proj_b, (float*)d_out);
}

// Round 7
// 491.974 us; speedup vs baseline: 1.5452x; 1.0902x over previous
//
#include <hip/hip_runtime.h>

typedef __bf16 bf16;
typedef __bf16 bf16x8 __attribute__((ext_vector_type(8)));
typedef __bf16 bf16x4 __attribute__((ext_vector_type(4)));
typedef float  f32x4  __attribute__((ext_vector_type(4)));

__device__ __forceinline__ f32x4 mfma16(bf16x8 a, bf16x8 b, f32x4 c) {
    return __builtin_amdgcn_mfma_f32_16x16x32_bf16(a, b, c, 0, 0, 0);
}

__device__ __forceinline__ void gll16(const bf16* g, bf16* l) {
    __builtin_amdgcn_global_load_lds(
        (const __attribute__((address_space(1))) void*)g,
        (__attribute__((address_space(3))) void*)l, 16, 0, 0);
}

// ---------------- K0: weight repack (BqT scaled+deinterleaved, kvWT, projT) ----------------
__global__ __launch_bounds__(256) void prep_weights(
    const float* __restrict__ qkv_w, const float* __restrict__ qkv_b,
    const float* __restrict__ proj_w,
    bf16* __restrict__ BqT, bf16* __restrict__ kvWT, bf16* __restrict__ projWT,
    float* __restrict__ bkv)
{
    int i = blockIdx.x * 256 + threadIdx.x;
    if (i < 262144) {
        int c_ = i >> 9, k = i & 511;
        int c = (c_ >> 6) * 192 + (c_ & 63) * 3;
        BqT[i] = (bf16)(qkv_w[k * 1536 + c] * 0.125f);
        return;
    }
    i -= 262144;
    if (i < 131072) {
        int c2 = i >> 9, k = i & 511;
        int t = c2 >> 7, kk = (c2 >> 6) & 1, e = c2 & 63;
        int c = t * 192 + e * 3 + 1 + kk;
        kvWT[i] = (bf16)(qkv_w[k * 1536 + c]);
        return;
    }
    i -= 131072;
    if (i < 262144) {
        int c_ = i >> 9, k = i & 511;
        projWT[i] = (bf16)(proj_w[k * 512 + c_]);
        return;
    }
    i -= 262144;
    if (i < 256) {
        int t = i >> 7, kk = (i >> 6) & 1, e = i & 63;
        bkv[i] = qkv_b[t * 192 + e * 3 + 1 + kk];
    }
}

// ---------------- K0b: R = pe_w @ Wq_scaled [3][512], bq2 — block-parallel reduce ----------------
__global__ __launch_bounds__(256) void prep_r2(
    const float* __restrict__ qkv_w, const float* __restrict__ qkv_b,
    const float* __restrict__ pe_w, const float* __restrict__ pe_b,
    float* __restrict__ R, float* __restrict__ bq2)
{
    const int c = blockIdx.x;            // 512
    const int tid = threadIdx.x;
    const int qc = (c >> 6) * 192 + (c & 63) * 3;
    float p0 = 0.f, p1 = 0.f, p2 = 0.f, p3 = 0.f;
    for (int k = tid; k < 512; k += 256) {
        float wv = qkv_w[(size_t)k * 1536 + qc];
        p0 += wv * pe_w[k];
        p1 += wv * pe_w[512 + k];
        p2 += wv * pe_w[1024 + k];
        p3 += wv * pe_b[k];
    }
    #pragma unroll
    for (int m = 1; m < 64; m <<= 1) {
        p0 += __shfl_xor(p0, m);
        p1 += __shfl_xor(p1, m);
        p2 += __shfl_xor(p2, m);
        p3 += __shfl_xor(p3, m);
    }
    __shared__ float red[4][4];
    int w = tid >> 6;
    if ((tid & 63) == 0) { red[w][0] = p0; red[w][1] = p1; red[w][2] = p2; red[w][3] = p3; }
    __syncthreads();
    if (tid == 0) {
        float s0 = red[0][0] + red[1][0] + red[2][0] + red[3][0];
        float s1 = red[0][1] + red[1][1] + red[2][1] + red[3][1];
        float s2 = red[0][2] + red[1][2] + red[2][2] + red[3][2];
        float s3 = red[0][3] + red[1][3] + red[2][3] + red[3][3];
        R[0 * 512 + c] = 0.125f * s0;
        R[1 * 512 + c] = 0.125f * s1;
        R[2 * 512 + c] = 0.125f * s2;
        bq2[c] = 0.125f * (qkv_b[qc] + s3);
    }
}

// ---------------- K0c: rel[t][3] = pos - ball mean ----------------
__global__ __launch_bounds__(64) void relprep(const float* __restrict__ pos,
                                              float* __restrict__ rel)
{
    const int t = blockIdx.x * 64 + threadIdx.x;
    float p0 = pos[(size_t)t * 3 + 0];
    float p1 = pos[(size_t)t * 3 + 1];
    float p2 = pos[(size_t)t * 3 + 2];
    float s0 = p0, s1 = p1, s2 = p2;
    #pragma unroll
    for (int m = 1; m < 64; m <<= 1) {
        s0 += __shfl_xor(s0, m);
        s1 += __shfl_xor(s1, m);
        s2 += __shfl_xor(s2, m);
    }
    rel[(size_t)t * 3 + 0] = p0 - s0 * (1.0f / 64.0f);
    rel[(size_t)t * 3 + 1] = p1 - s1 * (1.0f / 64.0f);
    rel[(size_t)t * 3 + 2] = p2 - s2 * (1.0f / 64.0f);
}

// ---------------- K1: Q = bf16(x') @ BqT^T (pe folded into epilogue) ----------------
// 128x128 tile, 4 waves, BK=64, SINGLE-buffer (4 blocks/CU), 2 barriers/K-step.
// A: f32 reg-staged with post-compute prefetch. B: global_load_lds, pre-swizzled src.
__global__ __launch_bounds__(256) void qgemm3(
    const float* __restrict__ X, const bf16* __restrict__ Bt,
    const float* __restrict__ rel, const float* __restrict__ R,
    const float* __restrict__ bq2, bf16* __restrict__ Qout)
{
    const int bid0 = blockIdx.x;
    const int wg = (bid0 & 7) * 512 + (bid0 >> 3);   // bijective XCD swizzle
    const int ct = wg & 3;
    const int rt = wg >> 2;
    const int row0 = rt * 128, col0 = ct * 128;
    const int tid = threadIdx.x;
    const int w = tid >> 6, l = tid & 63;
    const int wr = w >> 1, wc = w & 1;
    const int l15 = l & 15, lg = l >> 4;

    __shared__ __align__(16) bf16 As[8192];
    __shared__ __align__(16) bf16 Bs[8192];
    __shared__ float relS[128][3];
    __shared__ float RS[3][128];

    if (tid < 128) {
        relS[tid][0] = rel[(size_t)(row0 + tid) * 3 + 0];
        relS[tid][1] = rel[(size_t)(row0 + tid) * 3 + 1];
        relS[tid][2] = rel[(size_t)(row0 + tid) * 3 + 2];
    } else {
        int c = tid - 128;
        RS[0][c] = R[0 * 512 + col0 + c];
        RS[1][c] = R[1 * 512 + col0 + c];
        RS[2][c] = R[2 * 512 + col0 + c];
    }

    f32x4 acc[4][4] = {};

    // B staging geometry (src pre-swizzled, LDS dest linear)
    int srow[4], scol[4];
    #pragma unroll
    for (int j = 0; j < 4; ++j) {
        int chunk = w * 4 + j;
        int o = chunk * 512 + l * 8;
        int r = o >> 6;
        int slot = (o & 63) >> 3;
        srow[j] = r;
        scol[j] = ((slot ^ (r & 7)) << 3);
    }
    // A reg-staging geometry
    const int ar_sub = l >> 3;
    const int ak = l & 7;
    const int aslot = (ak ^ ar_sub) << 3;

    // prologue: A tile 0 into regs
    float4 va[4][2];
    #pragma unroll
    for (int j = 0; j < 4; ++j) {
        int r = (w * 4 + j) * 8 + ar_sub;
        const float* xp = X + (size_t)(row0 + r) * 512 + ak * 8;
        va[j][0] = *(const float4*)xp;
        va[j][1] = *(const float4*)(xp + 4);
    }

    for (int ki = 0; ki < 8; ++ki) {
        // stage: A cvt+ds_write from regs, B async gll16
        #pragma unroll
        for (int j = 0; j < 4; ++j) {
            int r = (w * 4 + j) * 8 + ar_sub;
            bf16x8 bv = { (bf16)va[j][0].x, (bf16)va[j][0].y, (bf16)va[j][0].z, (bf16)va[j][0].w,
                          (bf16)va[j][1].x, (bf16)va[j][1].y, (bf16)va[j][1].z, (bf16)va[j][1].w };
            *(bf16x8*)&As[r * 64 + aslot] = bv;
            gll16(Bt + (size_t)(col0 + srow[j]) * 512 + ki * 64 + scol[j], &Bs[(w * 4 + j) * 512]);
        }
        __syncthreads();

        #pragma unroll
        for (int kk = 0; kk < 2; ++kk) {
            bf16x8 a[4], b[4];
            #pragma unroll
            for (int mi = 0; mi < 4; ++mi) {
                int r = wr * 64 + mi * 16 + l15;
                int slot = (kk * 4 + lg) ^ (r & 7);
                a[mi] = *(const bf16x8*)&As[r * 64 + slot * 8];
            }
            #pragma unroll
            for (int ni = 0; ni < 4; ++ni) {
                int r = wc * 64 + ni * 16 + l15;
                int slot = (kk * 4 + lg) ^ (r & 7);
                b[ni] = *(const bf16x8*)&Bs[r * 64 + slot * 8];
            }
            #pragma unroll
            for (int mi = 0; mi < 4; ++mi)
                #pragma unroll
                for (int ni = 0; ni < 4; ++ni)
                    acc[mi][ni] = mfma16(a[mi], b[ni], acc[mi][ni]);
        }

        // prefetch next A tile into regs (issued pre-barrier, lands by next write)
        if (ki < 7) {
            int ks = (ki + 1) * 64;
            #pragma unroll
            for (int j = 0; j < 4; ++j) {
                int r = (w * 4 + j) * 8 + ar_sub;
                const float* xp = X + (size_t)(row0 + r) * 512 + ks + ak * 8;
                va[j][0] = *(const float4*)xp;
                va[j][1] = *(const float4*)(xp + 4);
            }
        }
        __syncthreads();
    }

    // epilogue: + bias + rel@R, direct bf16 stores
    #pragma unroll
    for (int mi = 0; mi < 4; ++mi) {
        #pragma unroll
        for (int ni = 0; ni < 4; ++ni) {
            int colL = wc * 64 + ni * 16 + l15;
            int col = col0 + colL;
            float bv = bq2[col];
            float r0c = RS[0][colL], r1c = RS[1][colL], r2c = RS[2][colL];
            int rbaseL = wr * 64 + mi * 16 + lg * 4;
            #pragma unroll
            for (int r = 0; r < 4; ++r) {
                int rowL = rbaseL + r;
                float vv = acc[mi][ni][r] + bv
                         + relS[rowL][0] * r0c + relS[rowL][1] * r1c + relS[rowL][2] * r2c;
                Qout[(size_t)(row0 + rowL) * 512 + col] = (bf16)vv;
            }
        }
    }
}

// ---------------- K4: proj GEMM (A,B via gll16, f32 out), single-buffer ----------------
__global__ __launch_bounds__(256) void pgemm3(
    const bf16* __restrict__ A, const bf16* __restrict__ Bt,
    const float* __restrict__ bias, float* __restrict__ out)
{
    const int bid0 = blockIdx.x;
    const int wg = (bid0 & 7) * 512 + (bid0 >> 3);
    const int ct = wg & 3;
    const int rt = wg >> 2;
    const int row0 = rt * 128, col0 = ct * 128;
    const int tid = threadIdx.x;
    const int w = tid >> 6, l = tid & 63;
    const int wr = w >> 1, wc = w & 1;
    const int l15 = l & 15, lg = l >> 4;

    __shared__ __align__(16) bf16 As[8192];
    __shared__ __align__(16) bf16 Bs[8192];

    f32x4 acc[4][4] = {};

    int srow[4], scol[4];
    #pragma unroll
    for (int j = 0; j < 4; ++j) {
        int chunk = w * 4 + j;
        int o = chunk * 512 + l * 8;
        int r = o >> 6;
        int slot = (o & 63) >> 3;
        srow[j] = r;
        scol[j] = ((slot ^ (r & 7)) << 3);
    }

    for (int ki = 0; ki < 8; ++ki) {
        int ks = ki * 64;
        #pragma unroll
        for (int j = 0; j < 4; ++j) {
            gll16(A  + (size_t)(row0 + srow[j]) * 512 + ks + scol[j], &As[(w * 4 + j) * 512]);
            gll16(Bt + (size_t)(col0 + srow[j]) * 512 + ks + scol[j], &Bs[(w * 4 + j) * 512]);
        }
        __syncthreads();
        #pragma unroll
        for (int kk = 0; kk < 2; ++kk) {
            bf16x8 a[4], b[4];
            #pragma unroll
            for (int mi = 0; mi < 4; ++mi) {
                int r = wr * 64 + mi * 16 + l15;
                int slot = (kk * 4 + lg) ^ (r & 7);
                a[mi] = *(const bf16x8*)&As[r * 64 + slot * 8];
            }
            #pragma unroll
            for (int ni = 0; ni < 4; ++ni) {
                int r = wc * 64 + ni * 16 + l15;
                int slot = (kk * 4 + lg) ^ (r & 7);
                b[ni] = *(const bf16x8*)&Bs[r * 64 + slot * 8];
            }
            #pragma unroll
            for (int mi = 0; mi < 4; ++mi)
                #pragma unroll
                for (int ni = 0; ni < 4; ++ni)
                    acc[mi][ni] = mfma16(a[mi], b[ni], acc[mi][ni]);
        }
        __syncthreads();
    }

    #pragma unroll
    for (int mi = 0; mi < 4; ++mi) {
        #pragma unroll
        for (int ni = 0; ni < 4; ++ni) {
            int col = col0 + wc * 64 + ni * 16 + l15;
            float bv = bias[col];
            int rbase = row0 + wr * 64 + mi * 16 + lg * 4;
            #pragma unroll
            for (int r = 0; r < 4; ++r)
                out[(size_t)(rbase + r) * 512 + col] = acc[mi][ni][r] + bv;
        }
    }
}

// ---------------- K2: k_sel / v_selT (x' recomputed inline for 1024 tokens) ----------------
__global__ __launch_bounds__(256) void kv_proj2(
    const float* __restrict__ x, const float* __restrict__ rel,
    const float* __restrict__ pe_w, const float* __restrict__ pe_b,
    const bf16* __restrict__ kvWT, const float* __restrict__ bkv,
    bf16* __restrict__ ksel, bf16* __restrict__ vselT)
{
    const int bid = blockIdx.x;
    const int b = bid >> 9;
    const int ball = (bid >> 6) & 7;
    const int m2 = bid & 63;
    const size_t tok = (size_t)b * 65536 + ball * 64 + m2;
    const int tid = threadIdx.x;

    __shared__ __align__(16) bf16 xrow[512];
    __shared__ float relt[3];
    if (tid < 3) relt[tid] = rel[tok * 3 + tid];
    __syncthreads();
    for (int k = tid; k < 512; k += 256) {
        float v = x[tok * 512 + k] + relt[0] * pe_w[k] + relt[1] * pe_w[512 + k]
                + relt[2] * pe_w[1024 + k] + pe_b[k];
        xrow[k] = (bf16)v;
    }
    __syncthreads();

    float acc = 0.f;
    const bf16* wrp = kvWT + (size_t)tid * 512;
    #pragma unroll 8
    for (int k = 0; k < 512; k += 8) {
        bf16x8 wv = *(const bf16x8*)(wrp + k);
        bf16x8 xv = *(const bf16x8*)(&xrow[k]);
        #pragma unroll
        for (int j = 0; j < 8; ++j) acc += (float)xv[j] * (float)wv[j];
    }
    acc += bkv[tid];
    int t = tid >> 7, kk = (tid >> 6) & 1, e = tid & 63;
    if (kk == 0)
        ksel[((size_t)(b * 8 + ball) * 128 + t * 64 + m2) * 64 + e] = (bf16)acc;
    else
        vselT[((size_t)(b * 8 + ball) * 64 + e) * 128 + t * 64 + m2] = (bf16)acc;
}

// ---------------- K3: attention (128 fixed KV per (b,h)), vectorized O-store ----------------
__global__ __launch_bounds__(256) void attn_k(
    const bf16* __restrict__ q, const bf16* __restrict__ ksel,
    const bf16* __restrict__ vselT, bf16* __restrict__ attno)
{
    const int bid = blockIdx.x;      // 16384 = 16 bh * 1024 qtiles
    const int qt = bid & 1023;
    const int bh = bid >> 10;
    const int b = bh >> 3;
    const int h = bh & 7;
    const int tid = threadIdx.x;
    const int w = tid >> 6;
    const int l = tid & 63;
    const int l15 = l & 15, lg = l >> 4;

    __shared__ __align__(16) bf16 Ks[128][72];
    __shared__ __align__(16) bf16 Vt[64][136];
    __shared__ __align__(16) bf16 Pl[4][16][136];

    const bf16* kg = ksel + (size_t)(b * 8 + h) * 128 * 64;
    #pragma unroll
    for (int it = 0; it < 4; ++it) {
        int i = it * 256 + tid;
        int r = i >> 3, c8 = (i & 7) * 8;
        *(bf16x8*)&Ks[r][c8] = *(const bf16x8*)(kg + r * 64 + c8);
    }
    const bf16* vg = vselT + (size_t)(b * 8 + h) * 64 * 128;
    #pragma unroll
    for (int it = 0; it < 4; ++it) {
        int i = it * 256 + tid;
        int r = i >> 4, c8 = (i & 15) * 8;
        *(bf16x8*)&Vt[r][c8] = *(const bf16x8*)(vg + r * 128 + c8);
    }

    const size_t tokq = (size_t)b * 65536 + (size_t)qt * 64 + w * 16 + l15;
    const bf16* qp = q + tokq * 512 + h * 64 + lg * 8;
    bf16x8 qa0 = *(const bf16x8*)qp;
    bf16x8 qa1 = *(const bf16x8*)(qp + 32);

    __syncthreads();

    f32x4 s[8];
    #pragma unroll
    for (int kt = 0; kt < 8; ++kt) {
        f32x4 a0 = {0.f, 0.f, 0.f, 0.f};
        a0 = mfma16(qa0, *(const bf16x8*)&Ks[kt * 16 + l15][lg * 8], a0);
        a0 = mfma16(qa1, *(const bf16x8*)&Ks[kt * 16 + l15][32 + lg * 8], a0);
        s[kt] = a0;
    }

    #pragma unroll
    for (int r = 0; r < 4; ++r) {
        float mx = s[0][r];
        #pragma unroll
        for (int kt = 1; kt < 8; ++kt) mx = fmaxf(mx, s[kt][r]);
        mx = fmaxf(mx, __shfl_xor(mx, 1));
        mx = fmaxf(mx, __shfl_xor(mx, 2));
        mx = fmaxf(mx, __shfl_xor(mx, 4));
        mx = fmaxf(mx, __shfl_xor(mx, 8));
        float sum = 0.f;
        #pragma unroll
        for (int kt = 0; kt < 8; ++kt) {
            float p = __expf(s[kt][r] - mx);
            s[kt][r] = p;
            sum += p;
        }
        sum += __shfl_xor(sum, 1);
        sum += __shfl_xor(sum, 2);
        sum += __shfl_xor(sum, 4);
        sum += __shfl_xor(sum, 8);
        float inv = 1.0f / sum;
        int prow = lg * 4 + r;
        #pragma unroll
        for (int kt = 0; kt < 8; ++kt)
            Pl[w][prow][kt * 16 + l15] = (bf16)(s[kt][r] * inv);
    }

    __syncthreads();

    f32x4 o[4] = { {0,0,0,0}, {0,0,0,0}, {0,0,0,0}, {0,0,0,0} };
    #pragma unroll
    for (int kc = 0; kc < 4; ++kc) {
        bf16x8 pa = *(const bf16x8*)&Pl[w][l15][kc * 32 + lg * 8];
        #pragma unroll
        for (int et = 0; et < 4; ++et)
            o[et] = mfma16(pa, *(const bf16x8*)&Vt[et * 16 + l15][kc * 32 + lg * 8], o[et]);
    }

    // stage O back into this wave's Pl slice (dead after PV), then 16B stores
    #pragma unroll
    for (int et = 0; et < 4; ++et)
        #pragma unroll
        for (int r = 0; r < 4; ++r)
            Pl[w][lg * 4 + r][et * 16 + l15] = (bf16)(o[et][r]);

    __syncthreads();

    {
        int rowg = tid >> 2;
        int w2 = rowg >> 4, lr = rowg & 15;
        int chunk = tid & 3;
        const size_t tok = (size_t)b * 65536 + (size_t)qt * 64 + rowg;
        bf16* gp = attno + tok * 512 + h * 64 + chunk * 16;
        const bf16* lp = &Pl[w2][lr][chunk * 16];
        *(bf16x8*)(gp + 0) = *(const bf16x8*)(lp + 0);
        *(bf16x8*)(gp + 8) = *(const bf16x8*)(lp + 8);
    }
}

extern "C" void kernel_launch(void* const* d_in, const int* in_sizes, int n_in,
                              void* d_out, int out_size, void* d_ws, size_t ws_size,
                              hipStream_t stream) {
    (void)in_sizes; (void)n_in; (void)out_size; (void)ws_size;
    const float* x      = (const float*)d_in[0];
    const float* pos    = (const float*)d_in[1];
    const float* qkv_w  = (const float*)d_in[2];
    const float* qkv_b  = (const float*)d_in[3];
    const float* proj_w = (const float*)d_in[4];
    const float* proj_b = (const float*)d_in[5];
    const float* pe_w   = (const float*)d_in[6];
    const float* pe_b   = (const float*)d_in[7];

    char* ws = (char*)d_ws;
    bf16*  Q     = (bf16*)(ws);                          // 134217728
    bf16*  Z     = (bf16*)(ws + 134217728);              // 134217728 (attn out)
    bf16*  BqT   = (bf16*)(ws + 268435456);              // 524288
    bf16*  PjT   = (bf16*)(ws + 268959744);              // 524288
    bf16*  kvWT  = (bf16*)(ws + 269484032);              // 262144
    bf16*  ksel  = (bf16*)(ws + 269746176);              // 262144
    bf16*  vselT = (bf16*)(ws + 270008320);              // 262144
    float* rel   = (float*)(ws + 270270464);             // 1572864
    float* R     = (float*)(ws + 271843328);             // 6144
    float* bq2   = (float*)(ws + 271849472);             // 2048
    float* bkv   = (float*)(ws + 271851520);             // 1024

    prep_weights<<<2561, 256, 0, stream>>>(qkv_w, qkv_b, proj_w, BqT, kvWT, PjT, bkv);
    prep_r2<<<512, 256, 0, stream>>>(qkv_w, qkv_b, pe_w, pe_b, R, bq2);
    relprep<<<2048, 64, 0, stream>>>(pos, rel);
    qgemm3<<<4096, 256, 0, stream>>>(x, BqT, rel, R, bq2, Q);
    kv_proj2<<<1024, 256, 0, stream>>>(x, rel, pe_w, pe_b, kvWT, bkv, ksel, vselT);
    attn_k<<<16384, 256, 0, stream>>>(Q, ksel, vselT, Z);
    pgemm3<<<4096, 256, 0, stream>>>(Z, PjT, proj_b, (float*)d_out);
}

// Round 9
// 486.702 us; speedup vs baseline: 1.5619x; 1.0108x over previous
//
#include <hip/hip_runtime.h>

typedef __bf16 bf16;
typedef __bf16 bf16x8 __attribute__((ext_vector_type(8)));
typedef __bf16 bf16x4 __attribute__((ext_vector_type(4)));
typedef float  f32x4  __attribute__((ext_vector_type(4)));

__device__ __forceinline__ f32x4 mfma16(bf16x8 a, bf16x8 b, f32x4 c) {
    return __builtin_amdgcn_mfma_f32_16x16x32_bf16(a, b, c, 0, 0, 0);
}

__device__ __forceinline__ void gll16(const bf16* g, bf16* l) {
    __builtin_amdgcn_global_load_lds(
        (const __attribute__((address_space(1))) void*)g,
        (__attribute__((address_space(3))) void*)l, 16, 0, 0);
}

#define SCHED_FENCE() __builtin_amdgcn_sched_barrier(0)

// ---------------- K0: weight repack (BqT scaled+deinterleaved, kvWT, projT) ----------------
__global__ __launch_bounds__(256) void prep_weights(
    const float* __restrict__ qkv_w, const float* __restrict__ qkv_b,
    const float* __restrict__ proj_w,
    bf16* __restrict__ BqT, bf16* __restrict__ kvWT, bf16* __restrict__ projWT,
    float* __restrict__ bkv)
{
    int i = blockIdx.x * 256 + threadIdx.x;
    if (i < 262144) {
        int c_ = i >> 9, k = i & 511;
        int c = (c_ >> 6) * 192 + (c_ & 63) * 3;
        BqT[i] = (bf16)(qkv_w[k * 1536 + c] * 0.125f);
        return;
    }
    i -= 262144;
    if (i < 131072) {
        int c2 = i >> 9, k = i & 511;
        int t = c2 >> 7, kk = (c2 >> 6) & 1, e = c2 & 63;
        int c = t * 192 + e * 3 + 1 + kk;
        kvWT[i] = (bf16)(qkv_w[k * 1536 + c]);
        return;
    }
    i -= 131072;
    if (i < 262144) {
        int c_ = i >> 9, k = i & 511;
        projWT[i] = (bf16)(proj_w[k * 512 + c_]);
        return;
    }
    i -= 262144;
    if (i < 256) {
        int t = i >> 7, kk = (i >> 6) & 1, e = i & 63;
        bkv[i] = qkv_b[t * 192 + e * 3 + 1 + kk];
    }
}

// ---------------- K0b: R = pe_w @ Wq_scaled [3][512], bq2 — block-parallel reduce ----------------
__global__ __launch_bounds__(256) void prep_r2(
    const float* __restrict__ qkv_w, const float* __restrict__ qkv_b,
    const float* __restrict__ pe_w, const float* __restrict__ pe_b,
    float* __restrict__ R, float* __restrict__ bq2)
{
    const int c = blockIdx.x;            // 512
    const int tid = threadIdx.x;
    const int qc = (c >> 6) * 192 + (c & 63) * 3;
    float p0 = 0.f, p1 = 0.f, p2 = 0.f, p3 = 0.f;
    for (int k = tid; k < 512; k += 256) {
        float wv = qkv_w[(size_t)k * 1536 + qc];
        p0 += wv * pe_w[k];
        p1 += wv * pe_w[512 + k];
        p2 += wv * pe_w[1024 + k];
        p3 += wv * pe_b[k];
    }
    #pragma unroll
    for (int m = 1; m < 64; m <<= 1) {
        p0 += __shfl_xor(p0, m);
        p1 += __shfl_xor(p1, m);
        p2 += __shfl_xor(p2, m);
        p3 += __shfl_xor(p3, m);
    }
    __shared__ float red[4][4];
    int w = tid >> 6;
    if ((tid & 63) == 0) { red[w][0] = p0; red[w][1] = p1; red[w][2] = p2; red[w][3] = p3; }
    __syncthreads();
    if (tid == 0) {
        float s0 = red[0][0] + red[1][0] + red[2][0] + red[3][0];
        float s1 = red[0][1] + red[1][1] + red[2][1] + red[3][1];
        float s2 = red[0][2] + red[1][2] + red[2][2] + red[3][2];
        float s3 = red[0][3] + red[1][3] + red[2][3] + red[3][3];
        R[0 * 512 + c] = 0.125f * s0;
        R[1 * 512 + c] = 0.125f * s1;
        R[2 * 512 + c] = 0.125f * s2;
        bq2[c] = 0.125f * (qkv_b[qc] + s3);
    }
}

// ---------------- K0c: rel[t][3] = pos - ball mean ----------------
__global__ __launch_bounds__(64) void relprep(const float* __restrict__ pos,
                                              float* __restrict__ rel)
{
    const int t = blockIdx.x * 64 + threadIdx.x;
    float p0 = pos[(size_t)t * 3 + 0];
    float p1 = pos[(size_t)t * 3 + 1];
    float p2 = pos[(size_t)t * 3 + 2];
    float s0 = p0, s1 = p1, s2 = p2;
    #pragma unroll
    for (int m = 1; m < 64; m <<= 1) {
        s0 += __shfl_xor(s0, m);
        s1 += __shfl_xor(s1, m);
        s2 += __shfl_xor(s2, m);
    }
    rel[(size_t)t * 3 + 0] = p0 - s0 * (1.0f / 64.0f);
    rel[(size_t)t * 3 + 1] = p1 - s1 * (1.0f / 64.0f);
    rel[(size_t)t * 3 + 2] = p2 - s2 * (1.0f / 64.0f);
}

// ---------------- K1: Q = bf16(x') @ BqT^T (pe folded). Counted-vmcnt, sched-fenced ----------------
// A: f32 reg-staged, single LDS buffer. B: gll16 double-buffer.
// Per iter: [fence] ds_write A(t); issue A(t+1)+B(t+1) [fence];
// s_waitcnt vmcnt(12) lgkmcnt(0); s_barrier [fence]; MFMA(t) [fence]; s_barrier.
// sched_barrier(0) at every boundary pins the VMEM issue counts (R8 raced without).
__global__ __launch_bounds__(256) void qgemm5(
    const float* __restrict__ X, const bf16* __restrict__ Bt,
    const float* __restrict__ rel, const float* __restrict__ R,
    const float* __restrict__ bq2, bf16* __restrict__ Qout)
{
    const int bid0 = blockIdx.x;
    const int wg = (bid0 & 7) * 512 + (bid0 >> 3);   // bijective XCD swizzle
    const int ct = wg & 3;
    const int rt = wg >> 2;
    const int row0 = rt * 128, col0 = ct * 128;
    const int tid = threadIdx.x;
    const int w = tid >> 6, l = tid & 63;
    const int wr = w >> 1, wc = w & 1;
    const int l15 = l & 15, lg = l >> 4;

    __shared__ __align__(16) bf16 As[8192];
    __shared__ __align__(16) bf16 Bs[2][8192];
    __shared__ float relS[128][3];
    __shared__ float RS[3][128];

    if (tid < 128) {
        relS[tid][0] = rel[(size_t)(row0 + tid) * 3 + 0];
        relS[tid][1] = rel[(size_t)(row0 + tid) * 3 + 1];
        relS[tid][2] = rel[(size_t)(row0 + tid) * 3 + 2];
    } else {
        int c = tid - 128;
        RS[0][c] = R[0 * 512 + col0 + c];
        RS[1][c] = R[1 * 512 + col0 + c];
        RS[2][c] = R[2 * 512 + col0 + c];
    }

    f32x4 acc[4][4] = {};

    int srow[4], scol[4];
    #pragma unroll
    for (int j = 0; j < 4; ++j) {
        int chunk = w * 4 + j;
        int o = chunk * 512 + l * 8;
        int r = o >> 6;
        int slot = (o & 63) >> 3;
        srow[j] = r;
        scol[j] = ((slot ^ (r & 7)) << 3);
    }
    const int ar_sub = l >> 3;
    const int ak = l & 7;
    const int aslot = (ak ^ ar_sub) << 3;

    // prologue: A(0) -> regs, B(0) -> Bs[0]
    float4 va[4][2];
    #pragma unroll
    for (int j = 0; j < 4; ++j) {
        int r = (w * 4 + j) * 8 + ar_sub;
        const float* xp = X + (size_t)(row0 + r) * 512 + ak * 8;
        va[j][0] = *(const float4*)xp;
        va[j][1] = *(const float4*)(xp + 4);
        gll16(Bt + (size_t)(col0 + srow[j]) * 512 + scol[j], &Bs[0][(w * 4 + j) * 512]);
    }

    #pragma unroll 1
    for (int ki = 0; ki < 8; ++ki) {
        SCHED_FENCE();
        #pragma unroll
        for (int j = 0; j < 4; ++j) {
            int r = (w * 4 + j) * 8 + ar_sub;
            bf16x8 bv = { (bf16)va[j][0].x, (bf16)va[j][0].y, (bf16)va[j][0].z, (bf16)va[j][0].w,
                          (bf16)va[j][1].x, (bf16)va[j][1].y, (bf16)va[j][1].z, (bf16)va[j][1].w };
            *(bf16x8*)&As[r * 64 + aslot] = bv;
        }
        if (ki < 7) {
            int ks = (ki + 1) * 64;
            #pragma unroll
            for (int j = 0; j < 4; ++j) {
                int r = (w * 4 + j) * 8 + ar_sub;
                const float* xp = X + (size_t)(row0 + r) * 512 + ks + ak * 8;
                va[j][0] = *(const float4*)xp;
                va[j][1] = *(const float4*)(xp + 4);
                gll16(Bt + (size_t)(col0 + srow[j]) * 512 + ks + scol[j],
                      &Bs[(ki + 1) & 1][(w * 4 + j) * 512]);
            }
            SCHED_FENCE();
            asm volatile("s_waitcnt vmcnt(12) lgkmcnt(0)" ::: "memory");
        } else {
            SCHED_FENCE();
            asm volatile("s_waitcnt vmcnt(0) lgkmcnt(0)" ::: "memory");
        }
        __builtin_amdgcn_s_barrier();
        SCHED_FENCE();

        const bf16* Bsc = Bs[ki & 1];
        #pragma unroll
        for (int kk = 0; kk < 2; ++kk) {
            bf16x8 a[4], b[4];
            #pragma unroll
            for (int mi = 0; mi < 4; ++mi) {
                int r = wr * 64 + mi * 16 + l15;
                int slot = (kk * 4 + lg) ^ (r & 7);
                a[mi] = *(const bf16x8*)&As[r * 64 + slot * 8];
            }
            #pragma unroll
            for (int ni = 0; ni < 4; ++ni) {
                int r = wc * 64 + ni * 16 + l15;
                int slot = (kk * 4 + lg) ^ (r & 7);
                b[ni] = *(const bf16x8*)&Bsc[r * 64 + slot * 8];
            }
            #pragma unroll
            for (int mi = 0; mi < 4; ++mi)
                #pragma unroll
                for (int ni = 0; ni < 4; ++ni)
                    acc[mi][ni] = mfma16(a[mi], b[ni], acc[mi][ni]);
        }
        SCHED_FENCE();
        __builtin_amdgcn_s_barrier();
    }
    SCHED_FENCE();

    #pragma unroll
    for (int mi = 0; mi < 4; ++mi) {
        #pragma unroll
        for (int ni = 0; ni < 4; ++ni) {
            int colL = wc * 64 + ni * 16 + l15;
            int col = col0 + colL;
            float bv = bq2[col];
            float r0c = RS[0][colL], r1c = RS[1][colL], r2c = RS[2][colL];
            int rbaseL = wr * 64 + mi * 16 + lg * 4;
            #pragma unroll
            for (int r = 0; r < 4; ++r) {
                int rowL = rbaseL + r;
                float vv = acc[mi][ni][r] + bv
                         + relS[rowL][0] * r0c + relS[rowL][1] * r1c + relS[rowL][2] * r2c;
                Qout[(size_t)(row0 + rowL) * 512 + col] = (bf16)vv;
            }
        }
    }
}

// ---------------- K4: proj GEMM, counted-vmcnt, sched-fenced ----------------
__global__ __launch_bounds__(256) void pgemm5(
    const bf16* __restrict__ A, const bf16* __restrict__ Bt,
    const float* __restrict__ bias, float* __restrict__ out)
{
    const int bid0 = blockIdx.x;
    const int wg = (bid0 & 7) * 512 + (bid0 >> 3);
    const int ct = wg & 3;
    const int rt = wg >> 2;
    const int row0 = rt * 128, col0 = ct * 128;
    const int tid = threadIdx.x;
    const int w = tid >> 6, l = tid & 63;
    const int wr = w >> 1, wc = w & 1;
    const int l15 = l & 15, lg = l >> 4;

    __shared__ __align__(16) bf16 As[8192];
    __shared__ __align__(16) bf16 Bs[2][8192];

    f32x4 acc[4][4] = {};

    int srow[4], scol[4];
    #pragma unroll
    for (int j = 0; j < 4; ++j) {
        int chunk = w * 4 + j;
        int o = chunk * 512 + l * 8;
        int r = o >> 6;
        int slot = (o & 63) >> 3;
        srow[j] = r;
        scol[j] = ((slot ^ (r & 7)) << 3);
    }
    const int ar_sub = l >> 3;
    const int ak = l & 7;
    const int aslot = (ak ^ ar_sub) << 3;

    // prologue
    bf16x8 va[4];
    #pragma unroll
    for (int j = 0; j < 4; ++j) {
        int r = (w * 4 + j) * 8 + ar_sub;
        va[j] = *(const bf16x8*)(A + (size_t)(row0 + r) * 512 + ak * 8);
        gll16(Bt + (size_t)(col0 + srow[j]) * 512 + scol[j], &Bs[0][(w * 4 + j) * 512]);
    }

    #pragma unroll 1
    for (int ki = 0; ki < 8; ++ki) {
        SCHED_FENCE();
        #pragma unroll
        for (int j = 0; j < 4; ++j) {
            int r = (w * 4 + j) * 8 + ar_sub;
            *(bf16x8*)&As[r * 64 + aslot] = va[j];
        }
        if (ki < 7) {
            int ks = (ki + 1) * 64;
            #pragma unroll
            for (int j = 0; j < 4; ++j) {
                int r = (w * 4 + j) * 8 + ar_sub;
                va[j] = *(const bf16x8*)(A + (size_t)(row0 + r) * 512 + ks + ak * 8);
                gll16(Bt + (size_t)(col0 + srow[j]) * 512 + ks + scol[j],
                      &Bs[(ki + 1) & 1][(w * 4 + j) * 512]);
            }
            SCHED_FENCE();
            asm volatile("s_waitcnt vmcnt(8) lgkmcnt(0)" ::: "memory");
        } else {
            SCHED_FENCE();
            asm volatile("s_waitcnt vmcnt(0) lgkmcnt(0)" ::: "memory");
        }
        __builtin_amdgcn_s_barrier();
        SCHED_FENCE();

        const bf16* Bsc = Bs[ki & 1];
        #pragma unroll
        for (int kk = 0; kk < 2; ++kk) {
            bf16x8 a[4], b[4];
            #pragma unroll
            for (int mi = 0; mi < 4; ++mi) {
                int r = wr * 64 + mi * 16 + l15;
                int slot = (kk * 4 + lg) ^ (r & 7);
                a[mi] = *(const bf16x8*)&As[r * 64 + slot * 8];
            }
            #pragma unroll
            for (int ni = 0; ni < 4; ++ni) {
                int r = wc * 64 + ni * 16 + l15;
                int slot = (kk * 4 + lg) ^ (r & 7);
                b[ni] = *(const bf16x8*)&Bsc[r * 64 + slot * 8];
            }
            #pragma unroll
            for (int mi = 0; mi < 4; ++mi)
                #pragma unroll
                for (int ni = 0; ni < 4; ++ni)
                    acc[mi][ni] = mfma16(a[mi], b[ni], acc[mi][ni]);
        }
        SCHED_FENCE();
        __builtin_amdgcn_s_barrier();
    }
    SCHED_FENCE();

    #pragma unroll
    for (int mi = 0; mi < 4; ++mi) {
        #pragma unroll
        for (int ni = 0; ni < 4; ++ni) {
            int col = col0 + wc * 64 + ni * 16 + l15;
            float bv = bias[col];
            int rbase = row0 + wr * 64 + mi * 16 + lg * 4;
            #pragma unroll
            for (int r = 0; r < 4; ++r)
                out[(size_t)(rbase + r) * 512 + col] = acc[mi][ni][r] + bv;
        }
    }
}

// ---------------- K2: k_sel / v_selT (x' recomputed inline for 1024 tokens) ----------------
__global__ __launch_bounds__(256) void kv_proj2(
    const float* __restrict__ x, const float* __restrict__ rel,
    const float* __restrict__ pe_w, const float* __restrict__ pe_b,
    const bf16* __restrict__ kvWT, const float* __restrict__ bkv,
    bf16* __restrict__ ksel, bf16* __restrict__ vselT)
{
    const int bid = blockIdx.x;
    const int b = bid >> 9;
    const int ball = (bid >> 6) & 7;
    const int m2 = bid & 63;
    const size_t tok = (size_t)b * 65536 + ball * 64 + m2;
    const int tid = threadIdx.x;

    __shared__ __align__(16) bf16 xrow[512];
    __shared__ float relt[3];
    if (tid < 3) relt[tid] = rel[tok * 3 + tid];
    __syncthreads();
    for (int k = tid; k < 512; k += 256) {
        float v = x[tok * 512 + k] + relt[0] * pe_w[k] + relt[1] * pe_w[512 + k]
                + relt[2] * pe_w[1024 + k] + pe_b[k];
        xrow[k] = (bf16)v;
    }
    __syncthreads();

    float acc = 0.f;
    const bf16* wrp = kvWT + (size_t)tid * 512;
    #pragma unroll 8
    for (int k = 0; k < 512; k += 8) {
        bf16x8 wv = *(const bf16x8*)(wrp + k);
        bf16x8 xv = *(const bf16x8*)(&xrow[k]);
        #pragma unroll
        for (int j = 0; j < 8; ++j) acc += (float)xv[j] * (float)wv[j];
    }
    acc += bkv[tid];
    int t = tid >> 7, kk = (tid >> 6) & 1, e = tid & 63;
    if (kk == 0)
        ksel[((size_t)(b * 8 + ball) * 128 + t * 64 + m2) * 64 + e] = (bf16)acc;
    else
        vselT[((size_t)(b * 8 + ball) * 64 + e) * 128 + t * 64 + m2] = (bf16)acc;
}

// ---------------- K3: attention (128 fixed KV per (b,h)), vectorized O-store ----------------
__global__ __launch_bounds__(256) void attn_k(
    const bf16* __restrict__ q, const bf16* __restrict__ ksel,
    const bf16* __restrict__ vselT, bf16* __restrict__ attno)
{
    const int bid = blockIdx.x;      // 16384 = 16 bh * 1024 qtiles
    const int qt = bid & 1023;
    const int bh = bid >> 10;
    const int b = bh >> 3;
    const int h = bh & 7;
    const int tid = threadIdx.x;
    const int w = tid >> 6;
    const int l = tid & 63;
    const int l15 = l & 15, lg = l >> 4;

    __shared__ __align__(16) bf16 Ks[128][72];
    __shared__ __align__(16) bf16 Vt[64][136];
    __shared__ __align__(16) bf16 Pl[4][16][136];

    const bf16* kg = ksel + (size_t)(b * 8 + h) * 128 * 64;
    #pragma unroll
    for (int it = 0; it < 4; ++it) {
        int i = it * 256 + tid;
        int r = i >> 3, c8 = (i & 7) * 8;
        *(bf16x8*)&Ks[r][c8] = *(const bf16x8*)(kg + r * 64 + c8);
    }
    const bf16* vg = vselT + (size_t)(b * 8 + h) * 64 * 128;
    #pragma unroll
    for (int it = 0; it < 4; ++it) {
        int i = it * 256 + tid;
        int r = i >> 4, c8 = (i & 15) * 8;
        *(bf16x8*)&Vt[r][c8] = *(const bf16x8*)(vg + r * 128 + c8);
    }

    const size_t tokq = (size_t)b * 65536 + (size_t)qt * 64 + w * 16 + l15;
    const bf16* qp = q + tokq * 512 + h * 64 + lg * 8;
    bf16x8 qa0 = *(const bf16x8*)qp;
    bf16x8 qa1 = *(const bf16x8*)(qp + 32);

    __syncthreads();

    f32x4 s[8];
    #pragma unroll
    for (int kt = 0; kt < 8; ++kt) {
        f32x4 a0 = {0.f, 0.f, 0.f, 0.f};
        a0 = mfma16(qa0, *(const bf16x8*)&Ks[kt * 16 + l15][lg * 8], a0);
        a0 = mfma16(qa1, *(const bf16x8*)&Ks[kt * 16 + l15][32 + lg * 8], a0);
        s[kt] = a0;
    }

    #pragma unroll
    for (int r = 0; r < 4; ++r) {
        float mx = s[0][r];
        #pragma unroll
        for (int kt = 1; kt < 8; ++kt) mx = fmaxf(mx, s[kt][r]);
        mx = fmaxf(mx, __shfl_xor(mx, 1));
        mx = fmaxf(mx, __shfl_xor(mx, 2));
        mx = fmaxf(mx, __shfl_xor(mx, 4));
        mx = fmaxf(mx, __shfl_xor(mx, 8));
        float sum = 0.f;
        #pragma unroll
        for (int kt = 0; kt < 8; ++kt) {
            float p = __expf(s[kt][r] - mx);
            s[kt][r] = p;
            sum += p;
        }
        sum += __shfl_xor(sum, 1);
        sum += __shfl_xor(sum, 2);
        sum += __shfl_xor(sum, 4);
        sum += __shfl_xor(sum, 8);
        float inv = 1.0f / sum;
        int prow = lg * 4 + r;
        #pragma unroll
        for (int kt = 0; kt < 8; ++kt)
            Pl[w][prow][kt * 16 + l15] = (bf16)(s[kt][r] * inv);
    }

    __syncthreads();

    f32x4 o[4] = { {0,0,0,0}, {0,0,0,0}, {0,0,0,0}, {0,0,0,0} };
    #pragma unroll
    for (int kc = 0; kc < 4; ++kc) {
        bf16x8 pa = *(const bf16x8*)&Pl[w][l15][kc * 32 + lg * 8];
        #pragma unroll
        for (int et = 0; et < 4; ++et)
            o[et] = mfma16(pa, *(const bf16x8*)&Vt[et * 16 + l15][kc * 32 + lg * 8], o[et]);
    }

    #pragma unroll
    for (int et = 0; et < 4; ++et)
        #pragma unroll
        for (int r = 0; r < 4; ++r)
            Pl[w][lg * 4 + r][et * 16 + l15] = (bf16)(o[et][r]);

    __syncthreads();

    {
        int rowg = tid >> 2;
        int w2 = rowg >> 4, lr = rowg & 15;
        int chunk = tid & 3;
        const size_t tok = (size_t)b * 65536 + (size_t)qt * 64 + rowg;
        bf16* gp = attno + tok * 512 + h * 64 + chunk * 16;
        const bf16* lp = &Pl[w2][lr][chunk * 16];
        *(bf16x8*)(gp + 0) = *(const bf16x8*)(lp + 0);
        *(bf16x8*)(gp + 8) = *(const bf16x8*)(lp + 8);
    }
}

extern "C" void kernel_launch(void* const* d_in, const int* in_sizes, int n_in,
                              void* d_out, int out_size, void* d_ws, size_t ws_size,
                              hipStream_t stream) {
    (void)in_sizes; (void)n_in; (void)out_size; (void)ws_size;
    const float* x      = (const float*)d_in[0];
    const float* pos    = (const float*)d_in[1];
    const float* qkv_w  = (const float*)d_in[2];
    const float* qkv_b  = (const float*)d_in[3];
    const float* proj_w = (const float*)d_in[4];
    const float* proj_b = (const float*)d_in[5];
    const float* pe_w   = (const float*)d_in[6];
    const float* pe_b   = (const float*)d_in[7];

    char* ws = (char*)d_ws;
    bf16*  Q     = (bf16*)(ws);                          // 134217728
    bf16*  Z     = (bf16*)(ws + 134217728);              // 134217728 (attn out)
    bf16*  BqT   = (bf16*)(ws + 268435456);              // 524288
    bf16*  PjT   = (bf16*)(ws + 268959744);              // 524288
    bf16*  kvWT  = (bf16*)(ws + 269484032);              // 262144
    bf16*  ksel  = (bf16*)(ws + 269746176);              // 262144
    bf16*  vselT = (bf16*)(ws + 270008320);              // 262144
    float* rel   = (float*)(ws + 270270464);             // 1572864
    float* R     = (float*)(ws + 271843328);             // 6144
    float* bq2   = (float*)(ws + 271849472);             // 2048
    float* bkv   = (float*)(ws + 271851520);             // 1024

    prep_weights<<<2561, 256, 0, stream>>>(qkv_w, qkv_b, proj_w, BqT, kvWT, PjT, bkv);
    prep_r2<<<512, 256, 0, stream>>>(qkv_w, qkv_b, pe_w, pe_b, R, bq2);
    relprep<<<2048, 64, 0, stream>>>(pos, rel);
    qgemm5<<<4096, 256, 0, stream>>>(x, BqT, rel, R, bq2, Q);
    kv_proj2<<<1024, 256, 0, stream>>>(x, rel, pe_w, pe_b, kvWT, bkv, ksel, vselT);
    attn_k<<<16384, 256, 0, stream>>>(Q, ksel, vselT, Z);
    pgemm5<<<4096, 256, 0, stream>>>(Z, PjT, proj_b, (float*)d_out);
}

// Round 10
// 422.018 us; speedup vs baseline: 1.8013x; 1.1533x over previous
//
#include <hip/hip_runtime.h>

typedef __bf16 bf16;
typedef __bf16 bf16x8 __attribute__((ext_vector_type(8)));
typedef __bf16 bf16x4 __attribute__((ext_vector_type(4)));
typedef float  f32x4  __attribute__((ext_vector_type(4)));

__device__ __forceinline__ f32x4 mfma16(bf16x8 a, bf16x8 b, f32x4 c) {
    return __builtin_amdgcn_mfma_f32_16x16x32_bf16(a, b, c, 0, 0, 0);
}

__device__ __forceinline__ void gll16(const bf16* g, bf16* l) {
    __builtin_amdgcn_global_load_lds(
        (const __attribute__((address_space(1))) void*)g,
        (__attribute__((address_space(3))) void*)l, 16, 0, 0);
}

// ---------------- K0: weight repack (BqT scaled+deinterleaved, kvWT, projT) ----------------
__global__ __launch_bounds__(256) void prep_weights(
    const float* __restrict__ qkv_w, const float* __restrict__ qkv_b,
    const float* __restrict__ proj_w,
    bf16* __restrict__ BqT, bf16* __restrict__ kvWT, bf16* __restrict__ projWT,
    float* __restrict__ bkv)
{
    int i = blockIdx.x * 256 + threadIdx.x;
    if (i < 262144) {
        int c_ = i >> 9, k = i & 511;
        int c = (c_ >> 6) * 192 + (c_ & 63) * 3;
        BqT[i] = (bf16)(qkv_w[k * 1536 + c] * 0.125f);
        return;
    }
    i -= 262144;
    if (i < 131072) {
        int c2 = i >> 9, k = i & 511;
        int t = c2 >> 7, kk = (c2 >> 6) & 1, e = c2 & 63;
        int c = t * 192 + e * 3 + 1 + kk;
        kvWT[i] = (bf16)(qkv_w[k * 1536 + c]);
        return;
    }
    i -= 131072;
    if (i < 262144) {
        int c_ = i >> 9, k = i & 511;
        projWT[i] = (bf16)(proj_w[k * 512 + c_]);
        return;
    }
    i -= 262144;
    if (i < 256) {
        int t = i >> 7, kk = (i >> 6) & 1, e = i & 63;
        bkv[i] = qkv_b[t * 192 + e * 3 + 1 + kk];
    }
}

// ---------------- K0b: R = pe_w @ Wq_scaled [3][512], bq2 — block-parallel reduce ----------------
__global__ __launch_bounds__(256) void prep_r2(
    const float* __restrict__ qkv_w, const float* __restrict__ qkv_b,
    const float* __restrict__ pe_w, const float* __restrict__ pe_b,
    float* __restrict__ R, float* __restrict__ bq2)
{
    const int c = blockIdx.x;            // 512
    const int tid = threadIdx.x;
    const int qc = (c >> 6) * 192 + (c & 63) * 3;
    float p0 = 0.f, p1 = 0.f, p2 = 0.f, p3 = 0.f;
    for (int k = tid; k < 512; k += 256) {
        float wv = qkv_w[(size_t)k * 1536 + qc];
        p0 += wv * pe_w[k];
        p1 += wv * pe_w[512 + k];
        p2 += wv * pe_w[1024 + k];
        p3 += wv * pe_b[k];
    }
    #pragma unroll
    for (int m = 1; m < 64; m <<= 1) {
        p0 += __shfl_xor(p0, m);
        p1 += __shfl_xor(p1, m);
        p2 += __shfl_xor(p2, m);
        p3 += __shfl_xor(p3, m);
    }
    __shared__ float red[4][4];
    int w = tid >> 6;
    if ((tid & 63) == 0) { red[w][0] = p0; red[w][1] = p1; red[w][2] = p2; red[w][3] = p3; }
    __syncthreads();
    if (tid == 0) {
        float s0 = red[0][0] + red[1][0] + red[2][0] + red[3][0];
        float s1 = red[0][1] + red[1][1] + red[2][1] + red[3][1];
        float s2 = red[0][2] + red[1][2] + red[2][2] + red[3][2];
        float s3 = red[0][3] + red[1][3] + red[2][3] + red[3][3];
        R[0 * 512 + c] = 0.125f * s0;
        R[1 * 512 + c] = 0.125f * s1;
        R[2 * 512 + c] = 0.125f * s2;
        bq2[c] = 0.125f * (qkv_b[qc] + s3);
    }
}

// ---------------- K0c: rel[t][3] = pos - ball mean ----------------
__global__ __launch_bounds__(64) void relprep(const float* __restrict__ pos,
                                              float* __restrict__ rel)
{
    const int t = blockIdx.x * 64 + threadIdx.x;
    float p0 = pos[(size_t)t * 3 + 0];
    float p1 = pos[(size_t)t * 3 + 1];
    float p2 = pos[(size_t)t * 3 + 2];
    float s0 = p0, s1 = p1, s2 = p2;
    #pragma unroll
    for (int m = 1; m < 64; m <<= 1) {
        s0 += __shfl_xor(s0, m);
        s1 += __shfl_xor(s1, m);
        s2 += __shfl_xor(s2, m);
    }
    rel[(size_t)t * 3 + 0] = p0 - s0 * (1.0f / 64.0f);
    rel[(size_t)t * 3 + 1] = p1 - s1 * (1.0f / 64.0f);
    rel[(size_t)t * 3 + 2] = p2 - s2 * (1.0f / 64.0f);
}

// ---------------- K1: Q = bf16(x') @ BqT^T — FULL-N block (64 rows x 512 cols) ----------------
// 8 waves; wave w owns cols [w*64, w*64+64) with the proven 64x64 fragment geometry.
// A (f32 X) read ONCE per row (no col-tile redundancy), reg-staged -> swizzled ds_write.
// B (whole BqT panel, L2-resident) via gll16, pre-swizzled source, linear dest.
__global__ __launch_bounds__(512) void qgemm6(
    const float* __restrict__ X, const bf16* __restrict__ Bt,
    const float* __restrict__ rel, const float* __restrict__ R,
    const float* __restrict__ bq2, bf16* __restrict__ Qout)
{
    const int row0 = blockIdx.x * 64;
    const int tid = threadIdx.x;
    const int w = tid >> 6, l = tid & 63;
    const int l15 = l & 15, lg = l >> 4;

    __shared__ __align__(16) bf16 As[4096];      // 64 rows x 64 k (swizzled)
    __shared__ __align__(16) bf16 Bs[32768];     // 512 cols x 64 k (swizzled)

    f32x4 acc[4][4] = {};

    // A staging geometry: thread -> (row = tid>>3, k-slot = tid&7)
    const int arow = tid >> 3;
    const int aslot = ((tid & 7) ^ (arow & 7)) << 3;   // element offset of swizzled 16B slot
    const float* xrow_p = X + (size_t)(row0 + arow) * 512 + (tid & 7) * 8;

    // B staging: per wave, 8 gll16; lane-uniform swizzled source offset
    const int bsrow = l >> 3;                           // col within 8-col chunk
    const int bscol = (((l & 7) ^ (l >> 3)) << 3);      // swizzled k-offset (elements)

    // prologue: A(0) into regs
    float4 va0 = *(const float4*)xrow_p;
    float4 va1 = *(const float4*)(xrow_p + 4);

    for (int ki = 0; ki < 8; ++ki) {
        int ks = ki * 64;
        // stage A from regs (cvt+swizzled ds_write)
        {
            bf16x8 bv = { (bf16)va0.x, (bf16)va0.y, (bf16)va0.z, (bf16)va0.w,
                          (bf16)va1.x, (bf16)va1.y, (bf16)va1.z, (bf16)va1.w };
            *(bf16x8*)&As[arow * 64 + aslot] = bv;
        }
        // stage B: 8 chunks per wave, 8 cols each
        #pragma unroll
        for (int j = 0; j < 8; ++j) {
            int chunk = w * 8 + j;                      // 0..63, 8 cols each
            int col = chunk * 8 + bsrow;
            gll16(Bt + (size_t)col * 512 + ks + bscol, &Bs[chunk * 512]);
        }
        __syncthreads();

        #pragma unroll
        for (int kk = 0; kk < 2; ++kk) {
            bf16x8 a[4], b[4];
            #pragma unroll
            for (int mi = 0; mi < 4; ++mi) {
                int r = mi * 16 + l15;
                int slot = (kk * 4 + lg) ^ (r & 7);
                a[mi] = *(const bf16x8*)&As[r * 64 + slot * 8];
            }
            #pragma unroll
            for (int ni = 0; ni < 4; ++ni) {
                int r = w * 64 + ni * 16 + l15;
                int slot = (kk * 4 + lg) ^ (r & 7);
                b[ni] = *(const bf16x8*)&Bs[r * 64 + slot * 8];
            }
            #pragma unroll
            for (int mi = 0; mi < 4; ++mi)
                #pragma unroll
                for (int ni = 0; ni < 4; ++ni)
                    acc[mi][ni] = mfma16(a[mi], b[ni], acc[mi][ni]);
        }

        // prefetch next A into regs
        if (ki < 7) {
            va0 = *(const float4*)(xrow_p + (ki + 1) * 64);
            va1 = *(const float4*)(xrow_p + (ki + 1) * 64 + 4);
        }
        __syncthreads();
    }

    // stage epilogue constants through dead LDS: colpack[col]={bq2,R0,R1,R2}, relF[row][3]
    {
        float4 cp;
        cp.x = bq2[tid];
        cp.y = R[tid];
        cp.z = R[512 + tid];
        cp.w = R[1024 + tid];
        ((float4*)As)[tid >> 1] = (tid & 1) ? cp : cp;   // placeholder to keep flow simple
    }
    // NOTE: As holds 8 KB = exactly 512 float4; write directly:
    {
        float4 cp;
        cp.x = bq2[tid];
        cp.y = R[tid];
        cp.z = R[512 + tid];
        cp.w = R[1024 + tid];
        ((float4*)As)[tid] = cp;
    }
    if (tid < 64) {
        ((float*)Bs)[tid * 3 + 0] = rel[(size_t)(row0 + tid) * 3 + 0];
        ((float*)Bs)[tid * 3 + 1] = rel[(size_t)(row0 + tid) * 3 + 1];
        ((float*)Bs)[tid * 3 + 2] = rel[(size_t)(row0 + tid) * 3 + 2];
    }
    __syncthreads();

    #pragma unroll
    for (int mi = 0; mi < 4; ++mi) {
        float rl[4][3];
        #pragma unroll
        for (int r = 0; r < 4; ++r) {
            int rowL = mi * 16 + lg * 4 + r;
            rl[r][0] = ((const float*)Bs)[rowL * 3 + 0];
            rl[r][1] = ((const float*)Bs)[rowL * 3 + 1];
            rl[r][2] = ((const float*)Bs)[rowL * 3 + 2];
        }
        #pragma unroll
        for (int ni = 0; ni < 4; ++ni) {
            int col = w * 64 + ni * 16 + l15;
            float4 cp = ((const float4*)As)[col];
            #pragma unroll
            for (int r = 0; r < 4; ++r) {
                int rowL = mi * 16 + lg * 4 + r;
                float vv = acc[mi][ni][r] + cp.x
                         + rl[r][0] * cp.y + rl[r][1] * cp.z + rl[r][2] * cp.w;
                Qout[(size_t)(row0 + rowL) * 512 + col] = (bf16)vv;
            }
        }
    }
}

// ---------------- K4: proj GEMM — FULL-N block (64 x 512), both operands gll16 ----------------
__global__ __launch_bounds__(512) void pgemm6(
    const bf16* __restrict__ A, const bf16* __restrict__ Bt,
    const float* __restrict__ bias, float* __restrict__ out)
{
    const int row0 = blockIdx.x * 64;
    const int tid = threadIdx.x;
    const int w = tid >> 6, l = tid & 63;
    const int l15 = l & 15, lg = l >> 4;

    __shared__ __align__(16) bf16 As[4096];
    __shared__ __align__(16) bf16 Bs[32768];

    f32x4 acc[4][4] = {};

    const int bsrow = l >> 3;
    const int bscol = (((l & 7) ^ (l >> 3)) << 3);
    // A staging via gll16: one chunk per wave (8 rows x 64 k each)
    const int acol = (((l & 7) ^ (l >> 3)) << 3);       // same swizzle pattern

    for (int ki = 0; ki < 8; ++ki) {
        int ks = ki * 64;
        // A: 8 chunks (one per wave), rows w*8 + (l>>3)
        {
            int arow = w * 8 + bsrow;
            gll16(A + (size_t)(row0 + arow) * 512 + ks + acol, &As[w * 512]);
        }
        // B: 8 chunks per wave
        #pragma unroll
        for (int j = 0; j < 8; ++j) {
            int chunk = w * 8 + j;
            int col = chunk * 8 + bsrow;
            gll16(Bt + (size_t)col * 512 + ks + bscol, &Bs[chunk * 512]);
        }
        __syncthreads();

        #pragma unroll
        for (int kk = 0; kk < 2; ++kk) {
            bf16x8 a[4], b[4];
            #pragma unroll
            for (int mi = 0; mi < 4; ++mi) {
                int r = mi * 16 + l15;
                int slot = (kk * 4 + lg) ^ (r & 7);
                a[mi] = *(const bf16x8*)&As[r * 64 + slot * 8];
            }
            #pragma unroll
            for (int ni = 0; ni < 4; ++ni) {
                int r = w * 64 + ni * 16 + l15;
                int slot = (kk * 4 + lg) ^ (r & 7);
                b[ni] = *(const bf16x8*)&Bs[r * 64 + slot * 8];
            }
            #pragma unroll
            for (int mi = 0; mi < 4; ++mi)
                #pragma unroll
                for (int ni = 0; ni < 4; ++ni)
                    acc[mi][ni] = mfma16(a[mi], b[ni], acc[mi][ni]);
        }
        __syncthreads();
    }

    #pragma unroll
    for (int ni = 0; ni < 4; ++ni) {
        int col = w * 64 + ni * 16 + l15;
        float bv = bias[col];
        #pragma unroll
        for (int mi = 0; mi < 4; ++mi) {
            int rowL = mi * 16 + lg * 4;
            #pragma unroll
            for (int r = 0; r < 4; ++r)
                out[(size_t)(row0 + rowL + r) * 512 + col] = acc[mi][ni][r] + bv;
        }
    }
}

// ---------------- K2: k_sel / v_selT (x' recomputed inline for 1024 tokens) ----------------
__global__ __launch_bounds__(256) void kv_proj2(
    const float* __restrict__ x, const float* __restrict__ rel,
    const float* __restrict__ pe_w, const float* __restrict__ pe_b,
    const bf16* __restrict__ kvWT, const float* __restrict__ bkv,
    bf16* __restrict__ ksel, bf16* __restrict__ vselT)
{
    const int bid = blockIdx.x;
    const int b = bid >> 9;
    const int ball = (bid >> 6) & 7;
    const int m2 = bid & 63;
    const size_t tok = (size_t)b * 65536 + ball * 64 + m2;
    const int tid = threadIdx.x;

    __shared__ __align__(16) bf16 xrow[512];
    __shared__ float relt[3];
    if (tid < 3) relt[tid] = rel[tok * 3 + tid];
    __syncthreads();
    for (int k = tid; k < 512; k += 256) {
        float v = x[tok * 512 + k] + relt[0] * pe_w[k] + relt[1] * pe_w[512 + k]
                + relt[2] * pe_w[1024 + k] + pe_b[k];
        xrow[k] = (bf16)v;
    }
    __syncthreads();

    float acc = 0.f;
    const bf16* wrp = kvWT + (size_t)tid * 512;
    #pragma unroll 8
    for (int k = 0; k < 512; k += 8) {
        bf16x8 wv = *(const bf16x8*)(wrp + k);
        bf16x8 xv = *(const bf16x8*)(&xrow[k]);
        #pragma unroll
        for (int j = 0; j < 8; ++j) acc += (float)xv[j] * (float)wv[j];
    }
    acc += bkv[tid];
    int t = tid >> 7, kk = (tid >> 6) & 1, e = tid & 63;
    if (kk == 0)
        ksel[((size_t)(b * 8 + ball) * 128 + t * 64 + m2) * 64 + e] = (bf16)acc;
    else
        vselT[((size_t)(b * 8 + ball) * 64 + e) * 128 + t * 64 + m2] = (bf16)acc;
}

// ---------------- K3: attention, 4 q-tiles per block (K/V staged once) ----------------
__global__ __launch_bounds__(256) void attn4(
    const bf16* __restrict__ q, const bf16* __restrict__ ksel,
    const bf16* __restrict__ vselT, bf16* __restrict__ attno)
{
    const int bid = blockIdx.x;      // 4096 = 16 bh * 256 qgroups
    const int qg = bid & 255;
    const int bh = bid >> 8;
    const int b = bh >> 3;
    const int h = bh & 7;
    const int tid = threadIdx.x;
    const int w = tid >> 6;
    const int l = tid & 63;
    const int l15 = l & 15, lg = l >> 4;

    __shared__ __align__(16) bf16 Ks[128][72];
    __shared__ __align__(16) bf16 Vt[64][136];
    __shared__ __align__(16) bf16 Pl[4][16][136];

    const bf16* kg = ksel + (size_t)(b * 8 + h) * 128 * 64;
    #pragma unroll
    for (int it = 0; it < 4; ++it) {
        int i = it * 256 + tid;
        int r = i >> 3, c8 = (i & 7) * 8;
        *(bf16x8*)&Ks[r][c8] = *(const bf16x8*)(kg + r * 64 + c8);
    }
    const bf16* vg = vselT + (size_t)(b * 8 + h) * 64 * 128;
    #pragma unroll
    for (int it = 0; it < 4; ++it) {
        int i = it * 256 + tid;
        int r = i >> 4, c8 = (i & 15) * 8;
        *(bf16x8*)&Vt[r][c8] = *(const bf16x8*)(vg + r * 128 + c8);
    }
    __syncthreads();

    for (int qi = 0; qi < 4; ++qi) {
        const int qt = qg * 4 + qi;
        const size_t tokq = (size_t)b * 65536 + (size_t)qt * 64 + w * 16 + l15;
        const bf16* qp = q + tokq * 512 + h * 64 + lg * 8;
        bf16x8 qa0 = *(const bf16x8*)qp;
        bf16x8 qa1 = *(const bf16x8*)(qp + 32);

        f32x4 s[8];
        #pragma unroll
        for (int kt = 0; kt < 8; ++kt) {
            f32x4 a0 = {0.f, 0.f, 0.f, 0.f};
            a0 = mfma16(qa0, *(const bf16x8*)&Ks[kt * 16 + l15][lg * 8], a0);
            a0 = mfma16(qa1, *(const bf16x8*)&Ks[kt * 16 + l15][32 + lg * 8], a0);
            s[kt] = a0;
        }

        #pragma unroll
        for (int r = 0; r < 4; ++r) {
            float mx = s[0][r];
            #pragma unroll
            for (int kt = 1; kt < 8; ++kt) mx = fmaxf(mx, s[kt][r]);
            mx = fmaxf(mx, __shfl_xor(mx, 1));
            mx = fmaxf(mx, __shfl_xor(mx, 2));
            mx = fmaxf(mx, __shfl_xor(mx, 4));
            mx = fmaxf(mx, __shfl_xor(mx, 8));
            float sum = 0.f;
            #pragma unroll
            for (int kt = 0; kt < 8; ++kt) {
                float p = __expf(s[kt][r] - mx);
                s[kt][r] = p;
                sum += p;
            }
            sum += __shfl_xor(sum, 1);
            sum += __shfl_xor(sum, 2);
            sum += __shfl_xor(sum, 4);
            sum += __shfl_xor(sum, 8);
            float inv = 1.0f / sum;
            int prow = lg * 4 + r;
            #pragma unroll
            for (int kt = 0; kt < 8; ++kt)
                Pl[w][prow][kt * 16 + l15] = (bf16)(s[kt][r] * inv);
        }

        f32x4 o[4] = { {0,0,0,0}, {0,0,0,0}, {0,0,0,0}, {0,0,0,0} };
        #pragma unroll
        for (int kc = 0; kc < 4; ++kc) {
            bf16x8 pa = *(const bf16x8*)&Pl[w][l15][kc * 32 + lg * 8];
            #pragma unroll
            for (int et = 0; et < 4; ++et)
                o[et] = mfma16(pa, *(const bf16x8*)&Vt[et * 16 + l15][kc * 32 + lg * 8], o[et]);
        }

        // stage O into own Pl slice, then cross-wave vectorized store
        #pragma unroll
        for (int et = 0; et < 4; ++et)
            #pragma unroll
            for (int r = 0; r < 4; ++r)
                Pl[w][lg * 4 + r][et * 16 + l15] = (bf16)(o[et][r]);

        __syncthreads();
        {
            int rowg = tid >> 2;
            int w2 = rowg >> 4, lr = rowg & 15;
            int chunk = tid & 3;
            const size_t tok = (size_t)b * 65536 + (size_t)qt * 64 + rowg;
            bf16* gp = attno + tok * 512 + h * 64 + chunk * 16;
            const bf16* lp = &Pl[w2][lr][chunk * 16];
            *(bf16x8*)(gp + 0) = *(const bf16x8*)(lp + 0);
            *(bf16x8*)(gp + 8) = *(const bf16x8*)(lp + 8);
        }
        __syncthreads();
    }
}

extern "C" void kernel_launch(void* const* d_in, const int* in_sizes, int n_in,
                              void* d_out, int out_size, void* d_ws, size_t ws_size,
                              hipStream_t stream) {
    (void)in_sizes; (void)n_in; (void)out_size; (void)ws_size;
    const float* x      = (const float*)d_in[0];
    const float* pos    = (const float*)d_in[1];
    const float* qkv_w  = (const float*)d_in[2];
    const float* qkv_b  = (const float*)d_in[3];
    const float* proj_w = (const float*)d_in[4];
    const float* proj_b = (const float*)d_in[5];
    const float* pe_w   = (const float*)d_in[6];
    const float* pe_b   = (const float*)d_in[7];

    char* ws = (char*)d_ws;
    bf16*  Q     = (bf16*)(ws);                          // 134217728
    bf16*  Z     = (bf16*)(ws + 134217728);              // 134217728 (attn out)
    bf16*  BqT   = (bf16*)(ws + 268435456);              // 524288
    bf16*  PjT   = (bf16*)(ws + 268959744);              // 524288
    bf16*  kvWT  = (bf16*)(ws + 269484032);              // 262144
    bf16*  ksel  = (bf16*)(ws + 269746176);              // 262144
    bf16*  vselT = (bf16*)(ws + 270008320);              // 262144
    float* rel   = (float*)(ws + 270270464);             // 1572864
    float* R     = (float*)(ws + 271843328);             // 6144
    float* bq2   = (float*)(ws + 271849472);             // 2048
    float* bkv   = (float*)(ws + 271851520);             // 1024

    prep_weights<<<2561, 256, 0, stream>>>(qkv_w, qkv_b, proj_w, BqT, kvWT, PjT, bkv);
    prep_r2<<<512, 256, 0, stream>>>(qkv_w, qkv_b, pe_w, pe_b, R, bq2);
    relprep<<<2048, 64, 0, stream>>>(pos, rel);
    qgemm6<<<2048, 512, 0, stream>>>(x, BqT, rel, R, bq2, Q);
    kv_proj2<<<1024, 256, 0, stream>>>(x, rel, pe_w, pe_b, kvWT, bkv, ksel, vselT);
    attn4<<<4096, 256, 0, stream>>>(Q, ksel, vselT, Z);
    pgemm6<<<2048, 512, 0, stream>>>(Z, PjT, proj_b, (float*)d_out);
}

// Round 11
// 411.309 us; speedup vs baseline: 1.8482x; 1.0260x over previous
//
#include <hip/hip_runtime.h>

typedef __bf16 bf16;
typedef __bf16 bf16x8 __attribute__((ext_vector_type(8)));
typedef __bf16 bf16x4 __attribute__((ext_vector_type(4)));
typedef float  f32x4  __attribute__((ext_vector_type(4)));

__device__ __forceinline__ f32x4 mfma16(bf16x8 a, bf16x8 b, f32x4 c) {
    return __builtin_amdgcn_mfma_f32_16x16x32_bf16(a, b, c, 0, 0, 0);
}

__device__ __forceinline__ void gll16(const bf16* g, bf16* l) {
    __builtin_amdgcn_global_load_lds(
        (const __attribute__((address_space(1))) void*)g,
        (__attribute__((address_space(3))) void*)l, 16, 0, 0);
}

#define SCHED_FENCE() __builtin_amdgcn_sched_barrier(0)

// ---------------- K0: weight repack (BqT scaled+deinterleaved, kvWT, projT) ----------------
__global__ __launch_bounds__(256) void prep_weights(
    const float* __restrict__ qkv_w, const float* __restrict__ qkv_b,
    const float* __restrict__ proj_w,
    bf16* __restrict__ BqT, bf16* __restrict__ kvWT, bf16* __restrict__ projWT,
    float* __restrict__ bkv)
{
    int i = blockIdx.x * 256 + threadIdx.x;
    if (i < 262144) {
        int c_ = i >> 9, k = i & 511;
        int c = (c_ >> 6) * 192 + (c_ & 63) * 3;
        BqT[i] = (bf16)(qkv_w[k * 1536 + c] * 0.125f);
        return;
    }
    i -= 262144;
    if (i < 131072) {
        int c2 = i >> 9, k = i & 511;
        int t = c2 >> 7, kk = (c2 >> 6) & 1, e = c2 & 63;
        int c = t * 192 + e * 3 + 1 + kk;
        kvWT[i] = (bf16)(qkv_w[k * 1536 + c]);
        return;
    }
    i -= 131072;
    if (i < 262144) {
        int c_ = i >> 9, k = i & 511;
        projWT[i] = (bf16)(proj_w[k * 512 + c_]);
        return;
    }
    i -= 262144;
    if (i < 256) {
        int t = i >> 7, kk = (i >> 6) & 1, e = i & 63;
        bkv[i] = qkv_b[t * 192 + e * 3 + 1 + kk];
    }
}

// ---------------- K0b: R = pe_w @ Wq_scaled [3][512], bq2 — block-parallel reduce ----------------
__global__ __launch_bounds__(256) void prep_r2(
    const float* __restrict__ qkv_w, const float* __restrict__ qkv_b,
    const float* __restrict__ pe_w, const float* __restrict__ pe_b,
    float* __restrict__ R, float* __restrict__ bq2)
{
    const int c = blockIdx.x;            // 512
    const int tid = threadIdx.x;
    const int qc = (c >> 6) * 192 + (c & 63) * 3;
    float p0 = 0.f, p1 = 0.f, p2 = 0.f, p3 = 0.f;
    for (int k = tid; k < 512; k += 256) {
        float wv = qkv_w[(size_t)k * 1536 + qc];
        p0 += wv * pe_w[k];
        p1 += wv * pe_w[512 + k];
        p2 += wv * pe_w[1024 + k];
        p3 += wv * pe_b[k];
    }
    #pragma unroll
    for (int m = 1; m < 64; m <<= 1) {
        p0 += __shfl_xor(p0, m);
        p1 += __shfl_xor(p1, m);
        p2 += __shfl_xor(p2, m);
        p3 += __shfl_xor(p3, m);
    }
    __shared__ float red[4][4];
    int w = tid >> 6;
    if ((tid & 63) == 0) { red[w][0] = p0; red[w][1] = p1; red[w][2] = p2; red[w][3] = p3; }
    __syncthreads();
    if (tid == 0) {
        float s0 = red[0][0] + red[1][0] + red[2][0] + red[3][0];
        float s1 = red[0][1] + red[1][1] + red[2][1] + red[3][1];
        float s2 = red[0][2] + red[1][2] + red[2][2] + red[3][2];
        float s3 = red[0][3] + red[1][3] + red[2][3] + red[3][3];
        R[0 * 512 + c] = 0.125f * s0;
        R[1 * 512 + c] = 0.125f * s1;
        R[2 * 512 + c] = 0.125f * s2;
        bq2[c] = 0.125f * (qkv_b[qc] + s3);
    }
}

// ---------------- K0c: rel[t][3] = pos - ball mean ----------------
__global__ __launch_bounds__(64) void relprep(const float* __restrict__ pos,
                                              float* __restrict__ rel)
{
    const int t = blockIdx.x * 64 + threadIdx.x;
    float p0 = pos[(size_t)t * 3 + 0];
    float p1 = pos[(size_t)t * 3 + 1];
    float p2 = pos[(size_t)t * 3 + 2];
    float s0 = p0, s1 = p1, s2 = p2;
    #pragma unroll
    for (int m = 1; m < 64; m <<= 1) {
        s0 += __shfl_xor(s0, m);
        s1 += __shfl_xor(s1, m);
        s2 += __shfl_xor(s2, m);
    }
    rel[(size_t)t * 3 + 0] = p0 - s0 * (1.0f / 64.0f);
    rel[(size_t)t * 3 + 1] = p1 - s1 * (1.0f / 64.0f);
    rel[(size_t)t * 3 + 2] = p2 - s2 * (1.0f / 64.0f);
}

// ---------------- K1: Q = bf16(x') @ BqT^T — FULL-N block (64 rows x 512 cols) ----------------
__global__ __launch_bounds__(512) void qgemm6(
    const float* __restrict__ X, const bf16* __restrict__ Bt,
    const float* __restrict__ rel, const float* __restrict__ R,
    const float* __restrict__ bq2, bf16* __restrict__ Qout)
{
    const int row0 = blockIdx.x * 64;
    const int tid = threadIdx.x;
    const int w = tid >> 6, l = tid & 63;
    const int l15 = l & 15, lg = l >> 4;

    __shared__ __align__(16) bf16 As[4096];      // 64 rows x 64 k (swizzled)
    __shared__ __align__(16) bf16 Bs[32768];     // 512 cols x 64 k (swizzled)

    f32x4 acc[4][4] = {};

    const int arow = tid >> 3;
    const int aslot = ((tid & 7) ^ (arow & 7)) << 3;
    const float* xrow_p = X + (size_t)(row0 + arow) * 512 + (tid & 7) * 8;

    const int bsrow = l >> 3;
    const int bscol = (((l & 7) ^ (l >> 3)) << 3);

    float4 va0 = *(const float4*)xrow_p;
    float4 va1 = *(const float4*)(xrow_p + 4);

    for (int ki = 0; ki < 8; ++ki) {
        int ks = ki * 64;
        {
            bf16x8 bv = { (bf16)va0.x, (bf16)va0.y, (bf16)va0.z, (bf16)va0.w,
                          (bf16)va1.x, (bf16)va1.y, (bf16)va1.z, (bf16)va1.w };
            *(bf16x8*)&As[arow * 64 + aslot] = bv;
        }
        #pragma unroll
        for (int j = 0; j < 8; ++j) {
            int chunk = w * 8 + j;
            int col = chunk * 8 + bsrow;
            gll16(Bt + (size_t)col * 512 + ks + bscol, &Bs[chunk * 512]);
        }
        __syncthreads();

        #pragma unroll
        for (int kk = 0; kk < 2; ++kk) {
            bf16x8 a[4], b[4];
            #pragma unroll
            for (int mi = 0; mi < 4; ++mi) {
                int r = mi * 16 + l15;
                int slot = (kk * 4 + lg) ^ (r & 7);
                a[mi] = *(const bf16x8*)&As[r * 64 + slot * 8];
            }
            #pragma unroll
            for (int ni = 0; ni < 4; ++ni) {
                int r = w * 64 + ni * 16 + l15;
                int slot = (kk * 4 + lg) ^ (r & 7);
                b[ni] = *(const bf16x8*)&Bs[r * 64 + slot * 8];
            }
            #pragma unroll
            for (int mi = 0; mi < 4; ++mi)
                #pragma unroll
                for (int ni = 0; ni < 4; ++ni)
                    acc[mi][ni] = mfma16(a[mi], b[ni], acc[mi][ni]);
        }

        if (ki < 7) {
            va0 = *(const float4*)(xrow_p + (ki + 1) * 64);
            va1 = *(const float4*)(xrow_p + (ki + 1) * 64 + 4);
        }
        __syncthreads();
    }

    // epilogue constants through dead LDS
    {
        float4 cp;
        cp.x = bq2[tid];
        cp.y = R[tid];
        cp.z = R[512 + tid];
        cp.w = R[1024 + tid];
        ((float4*)As)[tid] = cp;
    }
    if (tid < 64) {
        ((float*)Bs)[tid * 3 + 0] = rel[(size_t)(row0 + tid) * 3 + 0];
        ((float*)Bs)[tid * 3 + 1] = rel[(size_t)(row0 + tid) * 3 + 1];
        ((float*)Bs)[tid * 3 + 2] = rel[(size_t)(row0 + tid) * 3 + 2];
    }
    __syncthreads();

    #pragma unroll
    for (int mi = 0; mi < 4; ++mi) {
        float rl[4][3];
        #pragma unroll
        for (int r = 0; r < 4; ++r) {
            int rowL = mi * 16 + lg * 4 + r;
            rl[r][0] = ((const float*)Bs)[rowL * 3 + 0];
            rl[r][1] = ((const float*)Bs)[rowL * 3 + 1];
            rl[r][2] = ((const float*)Bs)[rowL * 3 + 2];
        }
        #pragma unroll
        for (int ni = 0; ni < 4; ++ni) {
            int col = w * 64 + ni * 16 + l15;
            float4 cp = ((const float4*)As)[col];
            #pragma unroll
            for (int r = 0; r < 4; ++r) {
                int rowL = mi * 16 + lg * 4 + r;
                float vv = acc[mi][ni][r] + cp.x
                         + rl[r][0] * cp.y + rl[r][1] * cp.z + rl[r][2] * cp.w;
                Qout[(size_t)(row0 + rowL) * 512 + col] = (bf16)vv;
            }
        }
    }
}

// ---------------- K4: proj GEMM — 8-phase m201-style, 256x256 tile, BK=64 ----------------
// 8 waves (2Mx4N), per-wave 128x64 out, LDS 128KB (2 K-tile bufs, region-major layouts).
// Region-major LDS: A lds_row = qm*128 + wr*64 + miq*16+l15 ; B lds_row = qn*128 + wcol*32 + njq*16+l15.
// Phase (t,q): q0: stage A1(t+1) -> vmcnt(6) -> barrier -> read+MFMA quad0;
// q1: read quad1 || stage B1(t+1); q2: read quad2 || stage A0(t+2) [dead since q1];
// q3: read quad3 || stage B0(t+2) [dead since q2]. Counted vmcnt never 0 in steady state.
__global__ __launch_bounds__(512, 2) void pgemm8(
    const bf16* __restrict__ A, const bf16* __restrict__ Bt,
    const float* __restrict__ bias, float* __restrict__ out)
{
    const int bid = blockIdx.x;                  // 1024
    const int wg = (bid & 7) * 128 + (bid >> 3); // bijective XCD swizzle
    const int ct = wg & 1, rt = wg >> 1;
    const int row0 = rt * 256, col0 = ct * 256;
    const int tid = threadIdx.x;
    const int w = tid >> 6, l = tid & 63;
    const int wr = w >> 2, wcol = w & 3;
    const int l15 = l & 15, lg = l >> 4;

    __shared__ __align__(16) bf16 Ab[2][16384];  // 2 x 32 KB
    __shared__ __align__(16) bf16 Bb[2][16384];

    f32x4 acc[8][4] = {};

    // staging lane geometry (identical swizzle convention to all prior kernels)
    const int srr = w * 8 + (l >> 3);            // 0..63 per 64-row round
    const int sk  = ((l & 7) ^ (l >> 3)) << 3;   // pre-swizzled k element offset

    // A region qm of K-tile kt: lds rows [qm*128, +128) <-> global rows {qm*64..+64} u {128+qm*64..+64}
    auto stageA = [&](int kt, int qm) {
        bf16* dst = &Ab[kt & 1][(qm * 128 + srr) * 64];
        int ks = kt * 64;
        gll16(A + (size_t)(row0 + qm * 64 + srr) * 512 + ks + sk, dst);
        gll16(A + (size_t)(row0 + 128 + qm * 64 + srr) * 512 + ks + sk, dst + 4096);
    };
    // B region qn: lds rows [qn*128,+128) <-> global cols (rr>>5)*64 + qn*32 + (rr&31)
    auto stageB = [&](int kt, int qn) {
        bf16* dst = &Bb[kt & 1][(qn * 128 + srr) * 64];
        int ks = kt * 64;
        int gc0 = (srr >> 5) * 64 + qn * 32 + (srr & 31);
        int rr1 = 64 + srr;
        int gc1 = (rr1 >> 5) * 64 + qn * 32 + (rr1 & 31);
        gll16(Bt + (size_t)(col0 + gc0) * 512 + ks + sk, dst);
        gll16(Bt + (size_t)(col0 + gc1) * 512 + ks + sk, dst + 4096);
    };

    // prologue: tile0 all regions, tile1 regions 0 (issue order matters for vmcnt!)
    stageA(0, 0); stageB(0, 0);
    SCHED_FENCE();
    stageA(0, 1); stageB(0, 1);
    SCHED_FENCE();
    stageA(1, 0); stageB(1, 0);
    SCHED_FENCE();

    #pragma unroll 1
    for (int kt = 0; kt < 8; ++kt) {
        const bf16* Ac = Ab[kt & 1];
        const bf16* Bc = Bb[kt & 1];
        #pragma unroll
        for (int q = 0; q < 4; ++q) {
            const int qm = q >> 1, qn = q & 1;
            bf16x8 a[4][2], b[2][2];

            if (q == 0) {
                SCHED_FENCE();
                if (kt < 7) stageA(kt + 1, 1);
                SCHED_FENCE();
                if (kt < 7) asm volatile("s_waitcnt vmcnt(6)" ::: "memory");
                else        asm volatile("s_waitcnt vmcnt(0)" ::: "memory");
                SCHED_FENCE();
                __builtin_amdgcn_s_barrier();   // tile kt fully landed for ALL waves
                SCHED_FENCE();
                // ds_reads after the validating barrier
                #pragma unroll
                for (int miq = 0; miq < 4; ++miq) {
                    int lr = qm * 128 + wr * 64 + miq * 16 + l15;
                    #pragma unroll
                    for (int kk = 0; kk < 2; ++kk) {
                        int slot = (kk * 4 + lg) ^ (lr & 7);
                        a[miq][kk] = *(const bf16x8*)&Ac[lr * 64 + slot * 8];
                    }
                }
                #pragma unroll
                for (int njq = 0; njq < 2; ++njq) {
                    int lr = qn * 128 + wcol * 32 + njq * 16 + l15;
                    #pragma unroll
                    for (int kk = 0; kk < 2; ++kk) {
                        int slot = (kk * 4 + lg) ^ (lr & 7);
                        b[njq][kk] = *(const bf16x8*)&Bc[lr * 64 + slot * 8];
                    }
                }
            } else {
                // regions already validated at this tile's q0 barrier
                #pragma unroll
                for (int miq = 0; miq < 4; ++miq) {
                    int lr = qm * 128 + wr * 64 + miq * 16 + l15;
                    #pragma unroll
                    for (int kk = 0; kk < 2; ++kk) {
                        int slot = (kk * 4 + lg) ^ (lr & 7);
                        a[miq][kk] = *(const bf16x8*)&Ac[lr * 64 + slot * 8];
                    }
                }
                #pragma unroll
                for (int njq = 0; njq < 2; ++njq) {
                    int lr = qn * 128 + wcol * 32 + njq * 16 + l15;
                    #pragma unroll
                    for (int kk = 0; kk < 2; ++kk) {
                        int slot = (kk * 4 + lg) ^ (lr & 7);
                        b[njq][kk] = *(const bf16x8*)&Bc[lr * 64 + slot * 8];
                    }
                }
                SCHED_FENCE();
                if (q == 1) { if (kt < 7) stageB(kt + 1, 1); }
                else if (q == 2) { if (kt < 6) stageA(kt + 2, 0); }
                else { if (kt < 6) stageB(kt + 2, 0); }
                SCHED_FENCE();
                __builtin_amdgcn_s_barrier();
            }

            asm volatile("s_waitcnt lgkmcnt(0)" ::: "memory");
            SCHED_FENCE();
            __builtin_amdgcn_s_setprio(1);
            #pragma unroll
            for (int miq = 0; miq < 4; ++miq)
                #pragma unroll
                for (int njq = 0; njq < 2; ++njq)
                    #pragma unroll
                    for (int kk = 0; kk < 2; ++kk)
                        acc[qm * 4 + miq][qn * 2 + njq] =
                            mfma16(a[miq][kk], b[njq][kk], acc[qm * 4 + miq][qn * 2 + njq]);
            __builtin_amdgcn_s_setprio(0);
            SCHED_FENCE();
            __builtin_amdgcn_s_barrier();
        }
    }
    SCHED_FENCE();

    #pragma unroll
    for (int ni = 0; ni < 4; ++ni) {
        int col = col0 + wcol * 64 + ni * 16 + l15;
        float bv = bias[col];
        #pragma unroll
        for (int mi = 0; mi < 8; ++mi) {
            size_t rbase = (size_t)row0 + wr * 128 + mi * 16 + lg * 4;
            #pragma unroll
            for (int r = 0; r < 4; ++r)
                out[(rbase + r) * 512 + col] = acc[mi][ni][r] + bv;
        }
    }
}

// ---------------- K2: k_sel / v_selT (x' recomputed inline for 1024 tokens) ----------------
__global__ __launch_bounds__(256) void kv_proj2(
    const float* __restrict__ x, const float* __restrict__ rel,
    const float* __restrict__ pe_w, const float* __restrict__ pe_b,
    const bf16* __restrict__ kvWT, const float* __restrict__ bkv,
    bf16* __restrict__ ksel, bf16* __restrict__ vselT)
{
    const int bid = blockIdx.x;
    const int b = bid >> 9;
    const int ball = (bid >> 6) & 7;
    const int m2 = bid & 63;
    const size_t tok = (size_t)b * 65536 + ball * 64 + m2;
    const int tid = threadIdx.x;

    __shared__ __align__(16) bf16 xrow[512];
    __shared__ float relt[3];
    if (tid < 3) relt[tid] = rel[tok * 3 + tid];
    __syncthreads();
    for (int k = tid; k < 512; k += 256) {
        float v = x[tok * 512 + k] + relt[0] * pe_w[k] + relt[1] * pe_w[512 + k]
                + relt[2] * pe_w[1024 + k] + pe_b[k];
        xrow[k] = (bf16)v;
    }
    __syncthreads();

    float acc = 0.f;
    const bf16* wrp = kvWT + (size_t)tid * 512;
    #pragma unroll 8
    for (int k = 0; k < 512; k += 8) {
        bf16x8 wv = *(const bf16x8*)(wrp + k);
        bf16x8 xv = *(const bf16x8*)(&xrow[k]);
        #pragma unroll
        for (int j = 0; j < 8; ++j) acc += (float)xv[j] * (float)wv[j];
    }
    acc += bkv[tid];
    int t = tid >> 7, kk = (tid >> 6) & 1, e = tid & 63;
    if (kk == 0)
        ksel[((size_t)(b * 8 + ball) * 128 + t * 64 + m2) * 64 + e] = (bf16)acc;
    else
        vselT[((size_t)(b * 8 + ball) * 64 + e) * 128 + t * 64 + m2] = (bf16)acc;
}

// ---------------- K3: attention, 4 q-tiles per block (K/V staged once) ----------------
__global__ __launch_bounds__(256) void attn4(
    const bf16* __restrict__ q, const bf16* __restrict__ ksel,
    const bf16* __restrict__ vselT, bf16* __restrict__ attno)
{
    const int bid = blockIdx.x;      // 4096 = 16 bh * 256 qgroups
    const int qg = bid & 255;
    const int bh = bid >> 8;
    const int b = bh >> 3;
    const int h = bh & 7;
    const int tid = threadIdx.x;
    const int w = tid >> 6;
    const int l = tid & 63;
    const int l15 = l & 15, lg = l >> 4;

    __shared__ __align__(16) bf16 Ks[128][72];
    __shared__ __align__(16) bf16 Vt[64][136];
    __shared__ __align__(16) bf16 Pl[4][16][136];

    const bf16* kg = ksel + (size_t)(b * 8 + h) * 128 * 64;
    #pragma unroll
    for (int it = 0; it < 4; ++it) {
        int i = it * 256 + tid;
        int r = i >> 3, c8 = (i & 7) * 8;
        *(bf16x8*)&Ks[r][c8] = *(const bf16x8*)(kg + r * 64 + c8);
    }
    const bf16* vg = vselT + (size_t)(b * 8 + h) * 64 * 128;
    #pragma unroll
    for (int it = 0; it < 4; ++it) {
        int i = it * 256 + tid;
        int r = i >> 4, c8 = (i & 15) * 8;
        *(bf16x8*)&Vt[r][c8] = *(const bf16x8*)(vg + r * 128 + c8);
    }
    __syncthreads();

    for (int qi = 0; qi < 4; ++qi) {
        const int qt = qg * 4 + qi;
        const size_t tokq = (size_t)b * 65536 + (size_t)qt * 64 + w * 16 + l15;
        const bf16* qp = q + tokq * 512 + h * 64 + lg * 8;
        bf16x8 qa0 = *(const bf16x8*)qp;
        bf16x8 qa1 = *(const bf16x8*)(qp + 32);

        f32x4 s[8];
        #pragma unroll
        for (int kt = 0; kt < 8; ++kt) {
            f32x4 a0 = {0.f, 0.f, 0.f, 0.f};
            a0 = mfma16(qa0, *(const bf16x8*)&Ks[kt * 16 + l15][lg * 8], a0);
            a0 = mfma16(qa1, *(const bf16x8*)&Ks[kt * 16 + l15][32 + lg * 8], a0);
            s[kt] = a0;
        }

        #pragma unroll
        for (int r = 0; r < 4; ++r) {
            float mx = s[0][r];
            #pragma unroll
            for (int kt = 1; kt < 8; ++kt) mx = fmaxf(mx, s[kt][r]);
            mx = fmaxf(mx, __shfl_xor(mx, 1));
            mx = fmaxf(mx, __shfl_xor(mx, 2));
            mx = fmaxf(mx, __shfl_xor(mx, 4));
            mx = fmaxf(mx, __shfl_xor(mx, 8));
            float sum = 0.f;
            #pragma unroll
            for (int kt = 0; kt < 8; ++kt) {
                float p = __expf(s[kt][r] - mx);
                s[kt][r] = p;
                sum += p;
            }
            sum += __shfl_xor(sum, 1);
            sum += __shfl_xor(sum, 2);
            sum += __shfl_xor(sum, 4);
            sum += __shfl_xor(sum, 8);
            float inv = 1.0f / sum;
            int prow = lg * 4 + r;
            #pragma unroll
            for (int kt = 0; kt < 8; ++kt)
                Pl[w][prow][kt * 16 + l15] = (bf16)(s[kt][r] * inv);
        }

        f32x4 o[4] = { {0,0,0,0}, {0,0,0,0}, {0,0,0,0}, {0,0,0,0} };
        #pragma unroll
        for (int kc = 0; kc < 4; ++kc) {
            bf16x8 pa = *(const bf16x8*)&Pl[w][l15][kc * 32 + lg * 8];
            #pragma unroll
            for (int et = 0; et < 4; ++et)
                o[et] = mfma16(pa, *(const bf16x8*)&Vt[et * 16 + l15][kc * 32 + lg * 8], o[et]);
        }

        #pragma unroll
        for (int et = 0; et < 4; ++et)
            #pragma unroll
            for (int r = 0; r < 4; ++r)
                Pl[w][lg * 4 + r][et * 16 + l15] = (bf16)(o[et][r]);

        __syncthreads();
        {
            int rowg = tid >> 2;
            int w2 = rowg >> 4, lr = rowg & 15;
            int chunk = tid & 3;
            const size_t tok = (size_t)b * 65536 + (size_t)qt * 64 + rowg;
            bf16* gp = attno + tok * 512 + h * 64 + chunk * 16;
            const bf16* lp = &Pl[w2][lr][chunk * 16];
            *(bf16x8*)(gp + 0) = *(const bf16x8*)(lp + 0);
            *(bf16x8*)(gp + 8) = *(const bf16x8*)(lp + 8);
        }
        __syncthreads();
    }
}

extern "C" void kernel_launch(void* const* d_in, const int* in_sizes, int n_in,
                              void* d_out, int out_size, void* d_ws, size_t ws_size,
                              hipStream_t stream) {
    (void)in_sizes; (void)n_in; (void)out_size; (void)ws_size;
    const float* x      = (const float*)d_in[0];
    const float* pos    = (const float*)d_in[1];
    const float* qkv_w  = (const float*)d_in[2];
    const float* qkv_b  = (const float*)d_in[3];
    const float* proj_w = (const float*)d_in[4];
    const float* proj_b = (const float*)d_in[5];
    const float* pe_w   = (const float*)d_in[6];
    const float* pe_b   = (const float*)d_in[7];

    char* ws = (char*)d_ws;
    bf16*  Q     = (bf16*)(ws);                          // 134217728
    bf16*  Z     = (bf16*)(ws + 134217728);              // 134217728 (attn out)
    bf16*  BqT   = (bf16*)(ws + 268435456);              // 524288
    bf16*  PjT   = (bf16*)(ws + 268959744);              // 524288
    bf16*  kvWT  = (bf16*)(ws + 269484032);              // 262144
    bf16*  ksel  = (bf16*)(ws + 269746176);              // 262144
    bf16*  vselT = (bf16*)(ws + 270008320);              // 262144
    float* rel   = (float*)(ws + 270270464);             // 1572864
    float* R     = (float*)(ws + 271843328);             // 6144
    float* bq2   = (float*)(ws + 271849472);             // 2048
    float* bkv   = (float*)(ws + 271851520);             // 1024

    prep_weights<<<2561, 256, 0, stream>>>(qkv_w, qkv_b, proj_w, BqT, kvWT, PjT, bkv);
    prep_r2<<<512, 256, 0, stream>>>(qkv_w, qkv_b, pe_w, pe_b, R, bq2);
    relprep<<<2048, 64, 0, stream>>>(pos, rel);
    qgemm6<<<2048, 512, 0, stream>>>(x, BqT, rel, R, bq2, Q);
    kv_proj2<<<1024, 256, 0, stream>>>(x, rel, pe_w, pe_b, kvWT, bkv, ksel, vselT);
    attn4<<<4096, 256, 0, stream>>>(Q, ksel, vselT, Z);
    pgemm8<<<1024, 512, 0, stream>>>(Z, PjT, proj_b, (float*)d_out);
}